// Round 3
// baseline (5051.710 us; speedup 1.0000x reference)
//
#include <hip/hip_runtime.h>
#include <hip/hip_bf16.h>

#define HID   1024
#define G3    3072
#define EMB   300
#define EMBP  320      // K padded to multiple of 32
#define VOCAB 3863
#define POSE  514
#define BATCH 128
#define TIN   64
#define TOUT  90
#define BH    (BATCH * HID)
#define NBLK  256

typedef __bf16 bf16x8 __attribute__((ext_vector_type(8)));
typedef float  f32x4  __attribute__((ext_vector_type(4)));
typedef __hip_bfloat16 bhalf;

#define MFMA(a,b,c) __builtin_amdgcn_mfma_f32_16x16x32_bf16((a),(b),(c),0,0,0)

__device__ __forceinline__ float sigm(float x) { return 1.f / (1.f + __expf(-x)); }
__device__ __forceinline__ float tanh_f(float x) { return 1.f - 2.f / (__expf(2.f * x) + 1.f); }

// ---- grid barrier: monotonic counter, release-add / acquire-fence (G16) ----
__device__ __forceinline__ void gbar(unsigned* bar, unsigned tgt) {
  __syncthreads();
  if (threadIdx.x == 0) {
    __hip_atomic_fetch_add(bar, 1u, __ATOMIC_RELEASE, __HIP_MEMORY_SCOPE_AGENT);
    while (__hip_atomic_load(bar, __ATOMIC_RELAXED, __HIP_MEMORY_SCOPE_AGENT) < tgt)
      __builtin_amdgcn_s_sleep(1);
  }
  __syncthreads();
  __builtin_amdgcn_fence(__ATOMIC_ACQUIRE, "agent");  // inv L1/L2 so fresh h is read
}

__global__ void k_zero32(unsigned* p) {
  if (threadIdx.x == 0 && blockIdx.x == 0)
    __hip_atomic_store(p, 0u, __ATOMIC_RELAXED, __HIP_MEMORY_SCOPE_AGENT);
}

// ---------- fp32 -> bf16 conversion with zero padding ----------
__global__ __launch_bounds__(256) void k_convert(const float* __restrict__ src,
        bhalf* __restrict__ dst, int rows_in, int cols_in, int cols_out, int total) {
  int i = blockIdx.x * 256 + threadIdx.x;
  if (i >= total) return;
  int r = i / cols_out, c = i - r * cols_out;
  float v = (r < rows_in && c < cols_in) ? src[(size_t)r * cols_in + c] : 0.f;
  dst[i] = __float2bfloat16(v);
}

// ---------- pack Whh [3H][H] -> [(j>>4)*48 + g*16 + (j&15)][k] bf16 ----------
__global__ __launch_bounds__(256) void k_pack(const float* __restrict__ whh,
                                              bhalf* __restrict__ dst) {
  int i = blockIdx.x * 256 + threadIdx.x;
  if (i >= G3 * HID) return;
  int k  = i & (HID - 1);
  int rp = i >> 10;
  int jg  = rp / 48;
  int rem = rp - jg * 48;
  int g = rem >> 4, jl = rem & 15;
  int j = (jg << 4) + jl;
  dst[i] = __float2bfloat16(whh[(size_t)((g << 10) + j) * HID + k]);
}

// ---------- MFMA GEMM-NT with bijective XCD-chunked swizzle ----------
__global__ __launch_bounds__(256) void k_gemm(
    const bhalf* __restrict__ A, const bhalf* __restrict__ B,
    const float* __restrict__ bias, float* __restrict__ C,
    int M, int K, int Nstore) {
  int gx = gridDim.x;
  int nwg = gx * gridDim.y;
  int orig = blockIdx.y * gx + blockIdx.x;
  int xcd = orig & 7, sl = orig >> 3;
  int qq = nwg >> 3, rr = nwg & 7;
  int nbid = (xcd < rr ? xcd * (qq + 1) : rr * (qq + 1) + (xcd - rr) * qq) + sl;
  int bx = nbid % gx, by = nbid / gx;

  int tid = threadIdx.x;
  int l = tid & 63, w = tid >> 6;
  int q = l >> 4, jl = l & 15;
  int n0 = bx * 32;
  int m0 = by * 128 + w * 32;
  int ar0 = m0 + jl;       if (ar0 >= M) ar0 = M - 1;
  int ar1 = m0 + 16 + jl;  if (ar1 >= M) ar1 = M - 1;
  const bhalf* pa0 = A + (size_t)ar0 * K + q * 8;
  const bhalf* pa1 = A + (size_t)ar1 * K + q * 8;
  const bhalf* pb0 = B + (size_t)(n0 + jl) * K + q * 8;
  const bhalf* pb1 = B + (size_t)(n0 + 16 + jl) * K + q * 8;
  f32x4 acc[2][2] = {};
#pragma unroll 4
  for (int kc = 0; kc < K; kc += 32) {
    bf16x8 a0 = *(const bf16x8*)(pa0 + kc);
    bf16x8 a1 = *(const bf16x8*)(pa1 + kc);
    bf16x8 b0 = *(const bf16x8*)(pb0 + kc);
    bf16x8 b1 = *(const bf16x8*)(pb1 + kc);
    acc[0][0] = MFMA(a0, b0, acc[0][0]);
    acc[0][1] = MFMA(a0, b1, acc[0][1]);
    acc[1][0] = MFMA(a1, b0, acc[1][0]);
    acc[1][1] = MFMA(a1, b1, acc[1][1]);
  }
#pragma unroll
  for (int sub = 0; sub < 2; ++sub)
#pragma unroll
    for (int ns = 0; ns < 2; ++ns)
#pragma unroll
      for (int reg = 0; reg < 4; ++reg) {
        int row = m0 + sub * 16 + q * 4 + reg;
        int col = n0 + ns * 16 + jl;
        if (row < M && col < Nstore)
          C[(size_t)row * Nstore + col] = acc[sub][ns][reg] + bias[col];
      }
}

// ---------- persistent kernel: 64 enc steps + handoff + 90 dec steps ----------
struct SeqArgs {
  const bhalf *packF, *packB, *packD;
  const float *tabF, *tabB, *tabD;   // fp32 gi tables (bih folded)
  const float *bhhF, *bhhB, *bhhD;
  const int *in_text, *poses;
  bhalf *hb0F, *hb1F, *hb0B, *hb1B;  // enc bf16 h ping-pong, per dir
  float *hfinF, *hfinB;              // enc final fp32 h
  bhalf *h0bf;                       // dec_h0 bf16
  bhalf *hs;                         // [90][128][1024] decoder hidden chain
  unsigned *bar;
};

__global__ __launch_bounds__(128, 1) void k_seq(SeqArgs A) {
  int tid = threadIdx.x;
  int l = tid & 63, w = tid >> 6;
  int q = l >> 4, jl = l & 15;
  int bid = blockIdx.x;
  unsigned tgt = 0;

  // ===== encoder mapping: bid = dir*128 + mh*64 + jg =====
  int dir = bid >> 7;
  int mh  = (bid >> 6) & 1;
  int jg  = bid & 63;
  int nb  = jg * 48;
  const bhalf* Bp  = dir ? A.packB : A.packF;
  const float* tab = dir ? A.tabB  : A.tabF;
  const float* bhh = dir ? A.bhhB  : A.bhhF;
  bhalf* hpp0 = dir ? A.hb0B : A.hb0F;
  bhalf* hpp1 = dir ? A.hb1B : A.hb1F;
  int m0 = mh * 64 + w * 32;
  int j  = jg * 16 + jl;
  float bhr = bhh[j], bhz = bhh[HID + j], bhn = bhh[2 * HID + j];

  // B-slice resident in VGPRs: 3 gates x 32 k-chunks x bf16x8 = 384 VGPR
  bf16x8 breg[3][32];
#pragma unroll
  for (int g = 0; g < 3; ++g) {
    const bhalf* bp = Bp + (size_t)(nb + g * 16 + jl) * HID + q * 8;
#pragma unroll
    for (int i = 0; i < 32; ++i) breg[g][i] = *(const bf16x8*)(bp + i * 32);
  }

  // zero my slice of ping buffer 0; fp32 h master lives in hreg only
  float hreg[8] = {};
  bhalf zb = __float2bfloat16(0.f);
#pragma unroll
  for (int sub = 0; sub < 2; ++sub)
#pragma unroll
    for (int reg = 0; reg < 4; ++reg) {
      int m = m0 + sub * 16 + q * 4 + reg;
      hpp0[(size_t)m * HID + j] = zb;
    }
  tgt += NBLK; gbar(A.bar, tgt);

  // ===== encoder: 64 steps =====
  for (int t = 0; t < TIN; ++t) {
    const bhalf* hcur = (t & 1) ? hpp1 : hpp0;
    bhalf*       hnxt = (t & 1) ? hpp0 : hpp1;
    const bhalf* pa0 = hcur + (size_t)(m0 + jl) * HID + q * 8;
    const bhalf* pa1 = hcur + (size_t)(m0 + 16 + jl) * HID + q * 8;
    f32x4 acc[2][3] = {};
#pragma unroll
    for (int i = 0; i < 32; ++i) {
      bf16x8 a0 = *(const bf16x8*)(pa0 + i * 32);
      bf16x8 a1 = *(const bf16x8*)(pa1 + i * 32);
      acc[0][0] = MFMA(a0, breg[0][i], acc[0][0]);
      acc[0][1] = MFMA(a0, breg[1][i], acc[0][1]);
      acc[0][2] = MFMA(a0, breg[2][i], acc[0][2]);
      acc[1][0] = MFMA(a1, breg[0][i], acc[1][0]);
      acc[1][1] = MFMA(a1, breg[1][i], acc[1][1]);
      acc[1][2] = MFMA(a1, breg[2][i], acc[1][2]);
    }
#pragma unroll
    for (int sub = 0; sub < 2; ++sub)
#pragma unroll
      for (int reg = 0; reg < 4; ++reg) {
        int idx = sub * 4 + reg;
        int m = m0 + sub * 16 + q * 4 + reg;
        int tok = A.in_text[m * TIN + t];
        const float* gi = tab + (size_t)tok * G3;
        float r = sigm(gi[j] + acc[sub][0][reg] + bhr);
        float z = sigm(gi[HID + j] + acc[sub][1][reg] + bhz);
        float n = tanh_f(gi[2 * HID + j] + r * (acc[sub][2][reg] + bhn));
        float hv = (1.f - z) * n + z * hreg[idx];
        hreg[idx] = hv;
        hnxt[(size_t)m * HID + j] = __float2bfloat16(hv);
      }
    tgt += NBLK; gbar(A.bar, tgt);
  }

  // ===== handoff: write final fp32 h =====
  {
    float* hfin = dir ? A.hfinB : A.hfinF;
#pragma unroll
    for (int sub = 0; sub < 2; ++sub)
#pragma unroll
      for (int reg = 0; reg < 4; ++reg) {
        int m = m0 + sub * 16 + q * 4 + reg;
        hfin[(size_t)m * HID + j] = hreg[sub * 4 + reg];
      }
  }
  tgt += NBLK; gbar(A.bar, tgt);

  // ===== decoder mapping: bid = mq*64 + jg2; wave covers 16 m-rows =====
  int jg2 = bid & 63, mq = bid >> 6;           // mq 0..3
  int nb2 = jg2 * 48;
  int m20 = mq * 32 + w * 16;
  int j2  = jg2 * 16 + jl;
  float b2r = A.bhhD[j2], b2z = A.bhhD[HID + j2], b2n = A.bhhD[2 * HID + j2];
#pragma unroll
  for (int g = 0; g < 3; ++g) {
    const bhalf* bp = A.packD + (size_t)(nb2 + g * 16 + jl) * HID + q * 8;
#pragma unroll
    for (int i = 0; i < 32; ++i) breg[g][i] = *(const bf16x8*)(bp + i * 32);
  }
  float hreg4[4];
#pragma unroll
  for (int reg = 0; reg < 4; ++reg) {
    int m = m20 + q * 4 + reg;
    float s = A.hfinF[(size_t)m * HID + j2] + A.hfinB[(size_t)m * HID + j2];
    hreg4[reg] = s;
    A.h0bf[(size_t)m * HID + j2] = __float2bfloat16(s);
  }
  tgt += NBLK; gbar(A.bar, tgt);

  // ===== decoder: 90 steps; bf16 h written straight into hs slab =====
  for (int t = 0; t < TOUT; ++t) {
    const bhalf* Asrc = t ? (A.hs + (size_t)(t - 1) * BH) : A.h0bf;
    const bhalf* pa = Asrc + (size_t)(m20 + jl) * HID + q * 8;
    f32x4 acc3[3] = {};
#pragma unroll
    for (int i = 0; i < 32; ++i) {
      bf16x8 a0 = *(const bf16x8*)(pa + i * 32);
      acc3[0] = MFMA(a0, breg[0][i], acc3[0]);
      acc3[1] = MFMA(a0, breg[1][i], acc3[1]);
      acc3[2] = MFMA(a0, breg[2][i], acc3[2]);
    }
    bhalf* hout = A.hs + (size_t)t * BH;
    int pt = t ? t - 1 : 0;
#pragma unroll
    for (int reg = 0; reg < 4; ++reg) {
      int m = m20 + q * 4 + reg;
      int tok = A.poses[m * TOUT + pt];
      const float* gi = A.tabD + (size_t)tok * G3;
      float r = sigm(gi[j2] + acc3[0][reg] + b2r);
      float z = sigm(gi[HID + j2] + acc3[1][reg] + b2z);
      float n = tanh_f(gi[2 * HID + j2] + r * (acc3[2][reg] + b2n));
      float hv = (1.f - z) * n + z * hreg4[reg];
      hreg4[reg] = hv;
      hout[(size_t)m * HID + j2] = __float2bfloat16(hv);
    }
    tgt += NBLK; gbar(A.bar, tgt);
  }
}

extern "C" void kernel_launch(void* const* d_in, const int* in_sizes, int n_in,
                              void* d_out, int out_size, void* d_ws, size_t ws_size,
                              hipStream_t stream) {
  const float* enc_emb   = (const float*)d_in[0];
  const float* enc_Wih_f = (const float*)d_in[1];
  const float* enc_Whh_f = (const float*)d_in[2];
  const float* enc_bih_f = (const float*)d_in[3];
  const float* enc_bhh_f = (const float*)d_in[4];
  const float* enc_Wih_b = (const float*)d_in[5];
  const float* enc_Whh_b = (const float*)d_in[6];
  const float* enc_bih_b = (const float*)d_in[7];
  const float* enc_bhh_b = (const float*)d_in[8];
  const float* dec_emb   = (const float*)d_in[9];
  const float* dec_Wih   = (const float*)d_in[10];
  const float* dec_Whh   = (const float*)d_in[11];
  const float* dec_bih   = (const float*)d_in[12];
  const float* dec_bhh   = (const float*)d_in[13];
  const float* fc_W      = (const float*)d_in[14];
  const float* fc_b      = (const float*)d_in[15];
  const int*   in_text   = (const int*)d_in[16];
  const int*   poses     = (const int*)d_in[18];
  float* out = (float*)d_out;

  char* p = (char*)d_ws;
  auto alloc = [&](size_t n) { char* r = p; p += (n + 255) & ~(size_t)255; return r; };
  float* tabF  = (float*)alloc((size_t)VOCAB * G3 * 4);
  float* tabB  = (float*)alloc((size_t)VOCAB * G3 * 4);
  float* tabD  = (float*)alloc((size_t)POSE * G3 * 4);
  bhalf* hb0F  = (bhalf*)alloc(BH * 2);
  bhalf* hb1F  = (bhalf*)alloc(BH * 2);
  bhalf* hb0B  = (bhalf*)alloc(BH * 2);
  bhalf* hb1B  = (bhalf*)alloc(BH * 2);
  float* hfinF = (float*)alloc(BH * 4);
  float* hfinB = (float*)alloc(BH * 4);
  bhalf* h0bf  = (bhalf*)alloc(BH * 2);
  bhalf* hs    = (bhalf*)alloc((size_t)TOUT * BH * 2);
  bhalf* embbf = (bhalf*)alloc((size_t)VOCAB * EMBP * 2);
  bhalf* wihF  = (bhalf*)alloc((size_t)G3 * EMBP * 2);
  bhalf* wihB  = (bhalf*)alloc((size_t)G3 * EMBP * 2);
  bhalf* dembbf= (bhalf*)alloc((size_t)POSE * HID * 2);
  bhalf* dwih  = (bhalf*)alloc((size_t)G3 * HID * 2);
  bhalf* fcw   = (bhalf*)alloc((size_t)544 * HID * 2);
  bhalf* packF = (bhalf*)alloc((size_t)G3 * HID * 2);
  bhalf* packB = (bhalf*)alloc((size_t)G3 * HID * 2);
  bhalf* packD = (bhalf*)alloc((size_t)G3 * HID * 2);
  unsigned* bar = (unsigned*)alloc(256);

  auto cgrid = [](int total) { return dim3((total + 255) / 256); };

  // one-off conversions / packing (+ barrier counter zero)
  k_zero32<<<1, 64, 0, stream>>>(bar);
  k_convert<<<cgrid(VOCAB * EMBP), 256, 0, stream>>>(enc_emb, embbf, VOCAB, EMB, EMBP, VOCAB * EMBP);
  k_convert<<<cgrid(G3 * EMBP),   256, 0, stream>>>(enc_Wih_f, wihF, G3, EMB, EMBP, G3 * EMBP);
  k_convert<<<cgrid(G3 * EMBP),   256, 0, stream>>>(enc_Wih_b, wihB, G3, EMB, EMBP, G3 * EMBP);
  k_convert<<<cgrid(POSE * HID),  256, 0, stream>>>(dec_emb, dembbf, POSE, HID, HID, POSE * HID);
  k_convert<<<cgrid(G3 * HID),    256, 0, stream>>>(dec_Wih, dwih, G3, HID, HID, G3 * HID);
  k_convert<<<cgrid(544 * HID),   256, 0, stream>>>(fc_W, fcw, POSE, HID, HID, 544 * HID);
  k_pack<<<cgrid(G3 * HID), 256, 0, stream>>>(enc_Whh_f, packF);
  k_pack<<<cgrid(G3 * HID), 256, 0, stream>>>(enc_Whh_b, packB);
  k_pack<<<cgrid(G3 * HID), 256, 0, stream>>>(dec_Whh, packD);

  // gi tables (fp32, bih folded)
  k_gemm<<<dim3(96, 31), 256, 0, stream>>>(embbf, wihF, enc_bih_f, tabF, VOCAB, EMBP, G3);
  k_gemm<<<dim3(96, 31), 256, 0, stream>>>(embbf, wihB, enc_bih_b, tabB, VOCAB, EMBP, G3);
  k_gemm<<<dim3(96, 5),  256, 0, stream>>>(dembbf, dwih, dec_bih, tabD, POSE, HID, G3);

  // persistent enc+dec (normal launch + hand-rolled grid barrier)
  SeqArgs sa;
  sa.packF = packF; sa.packB = packB; sa.packD = packD;
  sa.tabF = tabF; sa.tabB = tabB; sa.tabD = tabD;
  sa.bhhF = enc_bhh_f; sa.bhhB = enc_bhh_b; sa.bhhD = dec_bhh;
  sa.in_text = in_text; sa.poses = poses;
  sa.hb0F = hb0F; sa.hb1F = hb1F; sa.hb0B = hb0B; sa.hb1B = hb1B;
  sa.hfinF = hfinF; sa.hfinB = hfinB; sa.h0bf = h0bf; sa.hs = hs;
  sa.bar = bar;
  k_seq<<<dim3(NBLK), dim3(128), 0, stream>>>(sa);

  // output projection
  k_gemm<<<dim3(17, 90), 256, 0, stream>>>(hs, fcw, fc_b, out, TOUT * BATCH, HID, POSE);
}

// Round 5
// 2804.470 us; speedup vs baseline: 1.8013x; 1.8013x over previous
//
#include <hip/hip_runtime.h>
#include <hip/hip_bf16.h>

#define HID   1024
#define G3    3072
#define EMB   300
#define EMBP  320      // K padded to multiple of 32
#define VOCAB 3863
#define POSE  514
#define BATCH 128
#define TIN   64
#define TOUT  90
#define BH    (BATCH * HID)
#define NBLK  256

typedef __bf16 bf16x8 __attribute__((ext_vector_type(8)));
typedef float  f32x4  __attribute__((ext_vector_type(4)));
typedef __hip_bfloat16 bhalf;

#define MFMA(a,b,c) __builtin_amdgcn_mfma_f32_16x16x32_bf16((a),(b),(c),0,0,0)

__device__ __forceinline__ float sigm(float x) { return 1.f / (1.f + __expf(-x)); }
__device__ __forceinline__ float tanh_f(float x) { return 1.f - 2.f / (__expf(2.f * x) + 1.f); }

// ---- grid barrier: monotonic counter, release-add / acquire-fence (G16) ----
// proven on HW in round 3 (absmax == single-launch round 1)
__device__ __forceinline__ void gbar(unsigned* bar, unsigned tgt) {
  __syncthreads();
  if (threadIdx.x == 0) {
    __hip_atomic_fetch_add(bar, 1u, __ATOMIC_RELEASE, __HIP_MEMORY_SCOPE_AGENT);
    while (__hip_atomic_load(bar, __ATOMIC_RELAXED, __HIP_MEMORY_SCOPE_AGENT) < tgt)
      __builtin_amdgcn_s_sleep(1);
  }
  __syncthreads();
  __builtin_amdgcn_fence(__ATOMIC_ACQUIRE, "agent");  // inv L1/L2 so fresh h is read
}

__global__ void k_zerobar(unsigned* p) {
  int i = blockIdx.x * 256 + threadIdx.x;
  if (i < 1024)
    __hip_atomic_store(p + i, 0u, __ATOMIC_RELAXED, __HIP_MEMORY_SCOPE_AGENT);
}

// ---------- fp32 -> bf16 conversion with zero padding ----------
__global__ __launch_bounds__(256) void k_convert(const float* __restrict__ src,
        bhalf* __restrict__ dst, int rows_in, int cols_in, int cols_out, int total) {
  int i = blockIdx.x * 256 + threadIdx.x;
  if (i >= total) return;
  int r = i / cols_out, c = i - r * cols_out;
  float v = (r < rows_in && c < cols_in) ? src[(size_t)r * cols_in + c] : 0.f;
  dst[i] = __float2bfloat16(v);
}

// ---------- pack Whh [3H][H] -> [(j>>4)*48 + g*16 + (j&15)][k] bf16 ----------
__global__ __launch_bounds__(256) void k_pack(const float* __restrict__ whh,
                                              bhalf* __restrict__ dst) {
  int i = blockIdx.x * 256 + threadIdx.x;
  if (i >= G3 * HID) return;
  int k  = i & (HID - 1);
  int rp = i >> 10;
  int jg  = rp / 48;
  int rem = rp - jg * 48;
  int g = rem >> 4, jl = rem & 15;
  int j = (jg << 4) + jl;
  dst[i] = __float2bfloat16(whh[(size_t)((g << 10) + j) * HID + k]);
}

// ---------- MFMA GEMM-NT with bijective XCD-chunked swizzle ----------
__global__ __launch_bounds__(256) void k_gemm(
    const bhalf* __restrict__ A, const bhalf* __restrict__ B,
    const float* __restrict__ bias, float* __restrict__ C,
    int M, int K, int Nstore) {
  int gx = gridDim.x;
  int nwg = gx * gridDim.y;
  int orig = blockIdx.y * gx + blockIdx.x;
  int xcd = orig & 7, sl = orig >> 3;
  int qq = nwg >> 3, rr = nwg & 7;
  int nbid = (xcd < rr ? xcd * (qq + 1) : rr * (qq + 1) + (xcd - rr) * qq) + sl;
  int bx = nbid % gx, by = nbid / gx;

  int tid = threadIdx.x;
  int l = tid & 63, w = tid >> 6;
  int q = l >> 4, jl = l & 15;
  int n0 = bx * 32;
  int m0 = by * 128 + w * 32;
  int ar0 = m0 + jl;       if (ar0 >= M) ar0 = M - 1;
  int ar1 = m0 + 16 + jl;  if (ar1 >= M) ar1 = M - 1;
  const bhalf* pa0 = A + (size_t)ar0 * K + q * 8;
  const bhalf* pa1 = A + (size_t)ar1 * K + q * 8;
  const bhalf* pb0 = B + (size_t)(n0 + jl) * K + q * 8;
  const bhalf* pb1 = B + (size_t)(n0 + 16 + jl) * K + q * 8;
  f32x4 acc[2][2] = {};
#pragma unroll 4
  for (int kc = 0; kc < K; kc += 32) {
    bf16x8 a0 = *(const bf16x8*)(pa0 + kc);
    bf16x8 a1 = *(const bf16x8*)(pa1 + kc);
    bf16x8 b0 = *(const bf16x8*)(pb0 + kc);
    bf16x8 b1 = *(const bf16x8*)(pb1 + kc);
    acc[0][0] = MFMA(a0, b0, acc[0][0]);
    acc[0][1] = MFMA(a0, b1, acc[0][1]);
    acc[1][0] = MFMA(a1, b0, acc[1][0]);
    acc[1][1] = MFMA(a1, b1, acc[1][1]);
  }
#pragma unroll
  for (int sub = 0; sub < 2; ++sub)
#pragma unroll
    for (int ns = 0; ns < 2; ++ns)
#pragma unroll
      for (int reg = 0; reg < 4; ++reg) {
        int row = m0 + sub * 16 + q * 4 + reg;
        int col = n0 + ns * 16 + jl;
        if (row < M && col < Nstore)
          C[(size_t)row * Nstore + col] = acc[sub][ns][reg] + bias[col];
      }
}

// ---------- persistent kernel: 64 enc steps + handoff + 90 dec steps ----------
// block = 256 thr = 4 waves, each wave owns 16 j-cols (x3 gates) with weights
// register-resident (384 VGPR). Block covers 16 batch-rows x 64 j-cols.
// Sync domains: batch-row groups are independent chains -> domain = 16 blocks.
struct SeqArgs {
  const bhalf *packF, *packB, *packD;
  const float *tabF, *tabB, *tabD;   // fp32 gi tables (bih folded)
  const float *bhhF, *bhhB, *bhhD;
  const int *in_text, *poses;
  bhalf *hb0F, *hb1F, *hb0B, *hb1B;  // enc bf16 h ping-pong, per dir
  float *hfinF, *hfinB;              // enc final fp32 h
  bhalf *h0bf;                       // dec_h0 bf16
  bhalf *hs;                         // [90][128][1024] decoder hidden chain
  unsigned *barF, *barE, *barD;      // full / encoder-domain / decoder-domain
};

__global__ __launch_bounds__(256) __attribute__((amdgpu_waves_per_eu(1, 1)))
void k_seq(SeqArgs A) {
  int tid = threadIdx.x;
  int l = tid & 63, w = tid >> 6;
  int q = l >> 4, jl = l & 15;
  int bid = blockIdx.x;

  // ===== encoder mapping: bid = dir*128 + mg*16 + jb =====
  int dir = bid >> 7;
  int mg  = (bid >> 4) & 7;
  int jb  = bid & 15;
  int jwg = jb * 4 + w;          // 16-col group 0..63
  int nb  = jwg * 48;            // packed-B row base
  int m0  = mg * 16;
  int j   = jwg * 16 + jl;
  const bhalf* Bp  = dir ? A.packB : A.packF;
  const float* tab = dir ? A.tabB  : A.tabF;
  const float* bhh = dir ? A.bhhB  : A.bhhF;
  bhalf* hpp0 = dir ? A.hb0B : A.hb0F;
  bhalf* hpp1 = dir ? A.hb1B : A.hb1F;
  unsigned* myE = A.barE + (size_t)(dir * 8 + mg) * 32;   // 128B-padded counters
  float bhr = bhh[j], bhz = bhh[HID + j], bhn = bhh[2 * HID + j];

  // wave's B-slice resident in VGPRs: 3 gates x 32 k-chunks x 16B = 384 VGPR
  bf16x8 breg[3][32];
#pragma unroll
  for (int g = 0; g < 3; ++g) {
    const bhalf* bp = Bp + (size_t)(nb + g * 16 + jl) * HID + q * 8;
#pragma unroll
    for (int i = 0; i < 32; ++i) breg[g][i] = *(const bf16x8*)(bp + i * 32);
  }

  // zero my (m,j) slice of ping buffer 0; fp32 h master lives in hreg
  float hreg[4] = {};
  bhalf zb = __float2bfloat16(0.f);
#pragma unroll
  for (int reg = 0; reg < 4; ++reg)
    hpp0[(size_t)(m0 + q * 4 + reg) * HID + j] = zb;
  gbar(A.barF, NBLK);

  // ===== encoder: 64 steps =====
  unsigned et = 0;
  for (int t = 0; t < TIN; ++t) {
    const bhalf* hcur = (t & 1) ? hpp1 : hpp0;
    bhalf*       hnxt = (t & 1) ? hpp0 : hpp1;
    const bhalf* pa = hcur + (size_t)(m0 + jl) * HID + q * 8;
    f32x4 acc[3] = {};
#pragma unroll
    for (int i = 0; i < 32; ++i) {
      bf16x8 a0 = *(const bf16x8*)(pa + i * 32);
      acc[0] = MFMA(a0, breg[0][i], acc[0]);
      acc[1] = MFMA(a0, breg[1][i], acc[1]);
      acc[2] = MFMA(a0, breg[2][i], acc[2]);
    }
#pragma unroll
    for (int reg = 0; reg < 4; ++reg) {
      int m = m0 + q * 4 + reg;
      int tok = A.in_text[m * TIN + t];
      const float* gi = tab + (size_t)tok * G3;
      float r = sigm(gi[j] + acc[0][reg] + bhr);
      float z = sigm(gi[HID + j] + acc[1][reg] + bhz);
      float n = tanh_f(gi[2 * HID + j] + r * (acc[2][reg] + bhn));
      float hv = (1.f - z) * n + z * hreg[reg];
      hreg[reg] = hv;
      hnxt[(size_t)m * HID + j] = __float2bfloat16(hv);
    }
    et += 16;
    if (t < TIN - 1) gbar(myE, et);   // domain barrier: 16 blocks of (dir,mg)
  }

  // ===== handoff: final fp32 h -> hfin; full barrier =====
  {
    float* hfin = dir ? A.hfinB : A.hfinF;
#pragma unroll
    for (int reg = 0; reg < 4; ++reg)
      hfin[(size_t)(m0 + q * 4 + reg) * HID + j] = hreg[reg];
  }
  gbar(A.barF, 2 * NBLK);

  if (bid >= 128) return;   // decoder uses 128 blocks

  // ===== decoder mapping: bid = mg2*16 + jb2 =====
  int mg2 = bid >> 4;            // 0..7
  int jb2 = bid & 15;
  int jwg2 = jb2 * 4 + w;
  int nb2 = jwg2 * 48;
  int m20 = mg2 * 16;
  int j2  = jwg2 * 16 + jl;
  unsigned* myD = A.barD + (size_t)mg2 * 32;
  float b2r = A.bhhD[j2], b2z = A.bhhD[HID + j2], b2n = A.bhhD[2 * HID + j2];
#pragma unroll
  for (int g = 0; g < 3; ++g) {
    const bhalf* bp = A.packD + (size_t)(nb2 + g * 16 + jl) * HID + q * 8;
#pragma unroll
    for (int i = 0; i < 32; ++i) breg[g][i] = *(const bf16x8*)(bp + i * 32);
  }
  float hreg4[4];
#pragma unroll
  for (int reg = 0; reg < 4; ++reg) {
    int m = m20 + q * 4 + reg;
    float s = A.hfinF[(size_t)m * HID + j2] + A.hfinB[(size_t)m * HID + j2];
    hreg4[reg] = s;
    A.h0bf[(size_t)m * HID + j2] = __float2bfloat16(s);
  }
  unsigned dt = 16;
  gbar(myD, dt);                 // h0bf visible within domain

  // ===== decoder: 90 steps; bf16 h written straight into hs slab =====
  for (int t = 0; t < TOUT; ++t) {
    const bhalf* Asrc = t ? (A.hs + (size_t)(t - 1) * BH) : A.h0bf;
    const bhalf* pa = Asrc + (size_t)(m20 + jl) * HID + q * 8;
    f32x4 acc3[3] = {};
#pragma unroll
    for (int i = 0; i < 32; ++i) {
      bf16x8 a0 = *(const bf16x8*)(pa + i * 32);
      acc3[0] = MFMA(a0, breg[0][i], acc3[0]);
      acc3[1] = MFMA(a0, breg[1][i], acc3[1]);
      acc3[2] = MFMA(a0, breg[2][i], acc3[2]);
    }
    bhalf* hout = A.hs + (size_t)t * BH;
    int pt = t ? t - 1 : 0;
#pragma unroll
    for (int reg = 0; reg < 4; ++reg) {
      int m = m20 + q * 4 + reg;
      int tok = A.poses[m * TOUT + pt];
      const float* gi = A.tabD + (size_t)tok * G3;
      float r = sigm(gi[j2] + acc3[0][reg] + b2r);
      float z = sigm(gi[HID + j2] + acc3[1][reg] + b2z);
      float n = tanh_f(gi[2 * HID + j2] + r * (acc3[2][reg] + b2n));
      float hv = (1.f - z) * n + z * hreg4[reg];
      hreg4[reg] = hv;
      hout[(size_t)m * HID + j2] = __float2bfloat16(hv);
    }
    dt += 16;
    if (t < TOUT - 1) gbar(myD, dt);  // domain barrier: 16 blocks of mg2
  }
}

extern "C" void kernel_launch(void* const* d_in, const int* in_sizes, int n_in,
                              void* d_out, int out_size, void* d_ws, size_t ws_size,
                              hipStream_t stream) {
  const float* enc_emb   = (const float*)d_in[0];
  const float* enc_Wih_f = (const float*)d_in[1];
  const float* enc_Whh_f = (const float*)d_in[2];
  const float* enc_bih_f = (const float*)d_in[3];
  const float* enc_bhh_f = (const float*)d_in[4];
  const float* enc_Wih_b = (const float*)d_in[5];
  const float* enc_Whh_b = (const float*)d_in[6];
  const float* enc_bih_b = (const float*)d_in[7];
  const float* enc_bhh_b = (const float*)d_in[8];
  const float* dec_emb   = (const float*)d_in[9];
  const float* dec_Wih   = (const float*)d_in[10];
  const float* dec_Whh   = (const float*)d_in[11];
  const float* dec_bih   = (const float*)d_in[12];
  const float* dec_bhh   = (const float*)d_in[13];
  const float* fc_W      = (const float*)d_in[14];
  const float* fc_b      = (const float*)d_in[15];
  const int*   in_text   = (const int*)d_in[16];
  const int*   poses     = (const int*)d_in[18];
  float* out = (float*)d_out;

  char* p = (char*)d_ws;
  auto alloc = [&](size_t n) { char* r = p; p += (n + 255) & ~(size_t)255; return r; };
  float* tabF  = (float*)alloc((size_t)VOCAB * G3 * 4);
  float* tabB  = (float*)alloc((size_t)VOCAB * G3 * 4);
  float* tabD  = (float*)alloc((size_t)POSE * G3 * 4);
  bhalf* hb0F  = (bhalf*)alloc(BH * 2);
  bhalf* hb1F  = (bhalf*)alloc(BH * 2);
  bhalf* hb0B  = (bhalf*)alloc(BH * 2);
  bhalf* hb1B  = (bhalf*)alloc(BH * 2);
  float* hfinF = (float*)alloc(BH * 4);
  float* hfinB = (float*)alloc(BH * 4);
  bhalf* h0bf  = (bhalf*)alloc(BH * 2);
  bhalf* hs    = (bhalf*)alloc((size_t)TOUT * BH * 2);
  bhalf* embbf = (bhalf*)alloc((size_t)VOCAB * EMBP * 2);
  bhalf* wihF  = (bhalf*)alloc((size_t)G3 * EMBP * 2);
  bhalf* wihB  = (bhalf*)alloc((size_t)G3 * EMBP * 2);
  bhalf* dembbf= (bhalf*)alloc((size_t)POSE * HID * 2);
  bhalf* dwih  = (bhalf*)alloc((size_t)G3 * HID * 2);
  bhalf* fcw   = (bhalf*)alloc((size_t)544 * HID * 2);
  bhalf* packF = (bhalf*)alloc((size_t)G3 * HID * 2);
  bhalf* packB = (bhalf*)alloc((size_t)G3 * HID * 2);
  bhalf* packD = (bhalf*)alloc((size_t)G3 * HID * 2);
  unsigned* bars = (unsigned*)alloc(4096);
  unsigned* barF = bars;                // 1 counter (128B padded)
  unsigned* barE = bars + 32;           // 16 domain counters x 32 uints
  unsigned* barD = bars + 32 + 16 * 32; // 8 domain counters

  auto cgrid = [](int total) { return dim3((total + 255) / 256); };

  // one-off conversions / packing (+ barrier counters zero)
  k_zerobar<<<dim3(4), 256, 0, stream>>>(bars);
  k_convert<<<cgrid(VOCAB * EMBP), 256, 0, stream>>>(enc_emb, embbf, VOCAB, EMB, EMBP, VOCAB * EMBP);
  k_convert<<<cgrid(G3 * EMBP),   256, 0, stream>>>(enc_Wih_f, wihF, G3, EMB, EMBP, G3 * EMBP);
  k_convert<<<cgrid(G3 * EMBP),   256, 0, stream>>>(enc_Wih_b, wihB, G3, EMB, EMBP, G3 * EMBP);
  k_convert<<<cgrid(POSE * HID),  256, 0, stream>>>(dec_emb, dembbf, POSE, HID, HID, POSE * HID);
  k_convert<<<cgrid(G3 * HID),    256, 0, stream>>>(dec_Wih, dwih, G3, HID, HID, G3 * HID);
  k_convert<<<cgrid(544 * HID),   256, 0, stream>>>(fc_W, fcw, POSE, HID, HID, 544 * HID);
  k_pack<<<cgrid(G3 * HID), 256, 0, stream>>>(enc_Whh_f, packF);
  k_pack<<<cgrid(G3 * HID), 256, 0, stream>>>(enc_Whh_b, packB);
  k_pack<<<cgrid(G3 * HID), 256, 0, stream>>>(dec_Whh, packD);

  // gi tables (fp32, bih folded)
  k_gemm<<<dim3(96, 31), 256, 0, stream>>>(embbf, wihF, enc_bih_f, tabF, VOCAB, EMBP, G3);
  k_gemm<<<dim3(96, 31), 256, 0, stream>>>(embbf, wihB, enc_bih_b, tabB, VOCAB, EMBP, G3);
  k_gemm<<<dim3(96, 5),  256, 0, stream>>>(dembbf, dwih, dec_bih, tabD, POSE, HID, G3);

  // persistent enc+dec (normal launch + domain grid barriers)
  SeqArgs sa;
  sa.packF = packF; sa.packB = packB; sa.packD = packD;
  sa.tabF = tabF; sa.tabB = tabB; sa.tabD = tabD;
  sa.bhhF = enc_bhh_f; sa.bhhB = enc_bhh_b; sa.bhhD = dec_bhh;
  sa.in_text = in_text; sa.poses = poses;
  sa.hb0F = hb0F; sa.hb1F = hb1F; sa.hb0B = hb0B; sa.hb1B = hb1B;
  sa.hfinF = hfinF; sa.hfinB = hfinB; sa.h0bf = h0bf; sa.hs = hs;
  sa.barF = barF; sa.barE = barE; sa.barD = barD;
  k_seq<<<dim3(NBLK), dim3(256), 0, stream>>>(sa);

  // output projection
  k_gemm<<<dim3(17, 90), 256, 0, stream>>>(hs, fcw, fc_b, out, TOUT * BATCH, HID, POSE);
}

// Round 6
// 2642.502 us; speedup vs baseline: 1.9117x; 1.0613x over previous
//
#include <hip/hip_runtime.h>
#include <hip/hip_bf16.h>

#define HID   1024
#define G3    3072
#define EMB   300
#define EMBP  320      // K padded to multiple of 32
#define VOCAB 3863
#define POSE  514
#define BATCH 128
#define TIN   64
#define TOUT  90
#define BH    (BATCH * HID)
#define NBLK  256

typedef __bf16 bf16x8 __attribute__((ext_vector_type(8)));
typedef float  f32x4  __attribute__((ext_vector_type(4)));
typedef __hip_bfloat16 bhalf;
typedef unsigned long long u64;

#define MFMA(a,b,c) __builtin_amdgcn_mfma_f32_16x16x32_bf16((a),(b),(c),0,0,0)

__device__ __forceinline__ float sigm(float x) { return 1.f / (1.f + __expf(-x)); }
__device__ __forceinline__ float tanh_f(float x) { return 1.f - 2.f / (__expf(2.f * x) + 1.f); }

// ---- agent-coherent access helpers: sc0 sc1 loads/stores bypass stale L1/L2
// (same HW path as the proven spin counter) so NO cache-invalidating fence is
// needed at barriers -> weights/tables stay warm in L1/L2 across all steps.
__device__ __forceinline__ bf16x8 coh_ld16(const bhalf* p) {
  union { u64 u[2]; bf16x8 v; } r;
  r.u[0] = __hip_atomic_load((const u64*)p,     __ATOMIC_RELAXED, __HIP_MEMORY_SCOPE_AGENT);
  r.u[1] = __hip_atomic_load((const u64*)p + 1, __ATOMIC_RELAXED, __HIP_MEMORY_SCOPE_AGENT);
  return r.v;
}
__device__ __forceinline__ void coh_st_h(bhalf* p, float v) {
  union { bhalf b; unsigned short s; } u;
  u.b = __float2bfloat16(v);
  __hip_atomic_store((unsigned short*)p, u.s, __ATOMIC_RELAXED, __HIP_MEMORY_SCOPE_AGENT);
}
__device__ __forceinline__ void coh_st_f(float* p, float v) {
  __hip_atomic_store(p, v, __ATOMIC_RELAXED, __HIP_MEMORY_SCOPE_AGENT);
}
__device__ __forceinline__ float coh_ld_f(const float* p) {
  return __hip_atomic_load((const float*)p, __ATOMIC_RELAXED, __HIP_MEMORY_SCOPE_AGENT);
}

// ---- grid barrier WITHOUT acquire fence: release-add orders producer stores;
// consumers read shared h via coherent loads, so no cache inv required.
__device__ __forceinline__ void gbar(unsigned* bar, unsigned tgt) {
  __syncthreads();
  if (threadIdx.x == 0) {
    __hip_atomic_fetch_add(bar, 1u, __ATOMIC_RELEASE, __HIP_MEMORY_SCOPE_AGENT);
    while (__hip_atomic_load(bar, __ATOMIC_RELAXED, __HIP_MEMORY_SCOPE_AGENT) < tgt)
      __builtin_amdgcn_s_sleep(1);
  }
  __syncthreads();
  asm volatile("" ::: "memory");   // compiler ordering only
}

__global__ void k_zerobar(unsigned* p) {
  int i = blockIdx.x * 256 + threadIdx.x;
  if (i < 1024)
    __hip_atomic_store(p + i, 0u, __ATOMIC_RELAXED, __HIP_MEMORY_SCOPE_AGENT);
}

// ---------- fp32 -> bf16 conversion with zero padding ----------
__global__ __launch_bounds__(256) void k_convert(const float* __restrict__ src,
        bhalf* __restrict__ dst, int rows_in, int cols_in, int cols_out, int total) {
  int i = blockIdx.x * 256 + threadIdx.x;
  if (i >= total) return;
  int r = i / cols_out, c = i - r * cols_out;
  float v = (r < rows_in && c < cols_in) ? src[(size_t)r * cols_in + c] : 0.f;
  dst[i] = __float2bfloat16(v);
}

// ---------- pack Whh [3H][H] -> [(j>>4)*48 + g*16 + (j&15)][k] bf16 ----------
__global__ __launch_bounds__(256) void k_pack(const float* __restrict__ whh,
                                              bhalf* __restrict__ dst) {
  int i = blockIdx.x * 256 + threadIdx.x;
  if (i >= G3 * HID) return;
  int k  = i & (HID - 1);
  int rp = i >> 10;
  int jg  = rp / 48;
  int rem = rp - jg * 48;
  int g = rem >> 4, jl = rem & 15;
  int j = (jg << 4) + jl;
  dst[i] = __float2bfloat16(whh[(size_t)((g << 10) + j) * HID + k]);
}

// ---------- MFMA GEMM-NT, XCD-chunked swizzle; OUTBF: bf16 C vs f32 C ----------
template<int OUTBF>
__global__ __launch_bounds__(256) void k_gemm(
    const bhalf* __restrict__ A, const bhalf* __restrict__ B,
    const float* __restrict__ bias, float* __restrict__ Cf, bhalf* __restrict__ Cb,
    int M, int K, int Nstore) {
  int gx = gridDim.x;
  int nwg = gx * gridDim.y;
  int orig = blockIdx.y * gx + blockIdx.x;
  int xcd = orig & 7, sl = orig >> 3;
  int qq = nwg >> 3, rr = nwg & 7;
  int nbid = (xcd < rr ? xcd * (qq + 1) : rr * (qq + 1) + (xcd - rr) * qq) + sl;
  int bx = nbid % gx, by = nbid / gx;

  int tid = threadIdx.x;
  int l = tid & 63, w = tid >> 6;
  int q = l >> 4, jl = l & 15;
  int n0 = bx * 32;
  int m0 = by * 128 + w * 32;
  int ar0 = m0 + jl;       if (ar0 >= M) ar0 = M - 1;
  int ar1 = m0 + 16 + jl;  if (ar1 >= M) ar1 = M - 1;
  const bhalf* pa0 = A + (size_t)ar0 * K + q * 8;
  const bhalf* pa1 = A + (size_t)ar1 * K + q * 8;
  const bhalf* pb0 = B + (size_t)(n0 + jl) * K + q * 8;
  const bhalf* pb1 = B + (size_t)(n0 + 16 + jl) * K + q * 8;
  f32x4 acc[2][2] = {};
#pragma unroll 4
  for (int kc = 0; kc < K; kc += 32) {
    bf16x8 a0 = *(const bf16x8*)(pa0 + kc);
    bf16x8 a1 = *(const bf16x8*)(pa1 + kc);
    bf16x8 b0 = *(const bf16x8*)(pb0 + kc);
    bf16x8 b1 = *(const bf16x8*)(pb1 + kc);
    acc[0][0] = MFMA(a0, b0, acc[0][0]);
    acc[0][1] = MFMA(a0, b1, acc[0][1]);
    acc[1][0] = MFMA(a1, b0, acc[1][0]);
    acc[1][1] = MFMA(a1, b1, acc[1][1]);
  }
#pragma unroll
  for (int sub = 0; sub < 2; ++sub)
#pragma unroll
    for (int ns = 0; ns < 2; ++ns)
#pragma unroll
      for (int reg = 0; reg < 4; ++reg) {
        int row = m0 + sub * 16 + q * 4 + reg;
        int col = n0 + ns * 16 + jl;
        if (row < M && col < Nstore) {
          float v = acc[sub][ns][reg] + bias[col];
          if (OUTBF) Cb[(size_t)row * Nstore + col] = __float2bfloat16(v);
          else       Cf[(size_t)row * Nstore + col] = v;
        }
      }
}

// ---------- persistent kernel: 64 enc steps + handoff + 90 dec steps ----------
// 256 blocks x 512 thr (8 waves = 4 col-groups x 2 K-halves).
// Wave weight slice: 48 rows x 512 K = 192 VGPR -> fits 2 waves/SIMD budget
// (no spill). K-halves reduced via 12KB LDS. h exchanged via coherent ld/st.
struct SeqArgs {
  const bhalf *packF, *packB, *packD;
  const bhalf *tabF, *tabB, *tabD;   // bf16 gi tables (bih folded)
  const float *bhhF, *bhhB, *bhhD;
  const int *in_text, *poses;
  bhalf *hb0F, *hb1F, *hb0B, *hb1B;  // enc bf16 h ping-pong, per dir
  float *hfinF, *hfinB;              // enc final fp32 h
  bhalf *h0bf;                       // dec_h0 bf16
  bhalf *hs;                         // [90][128][1024] decoder hidden chain
  unsigned *barF, *barE, *barD;      // full / encoder-domain / decoder-domain
};

__global__ __launch_bounds__(512, 2) void k_seq(SeqArgs A) {
  __shared__ f32x4 red[4][3][64];    // col-group, gate, lane
  int tid = threadIdx.x;
  int l = tid & 63, w = tid >> 6;    // wave 0..7
  int q = l >> 4, jl = l & 15;
  int cg = w & 3, kh = w >> 2;       // col-group 0..3, K-half 0..1
  int kbase = kh * 512;
  int bid = blockIdx.x;

  // ===== encoder mapping: bid = dir*128 + mg*16 + jb =====
  int dir = bid >> 7;
  int mg  = (bid >> 4) & 7;
  int jb  = bid & 15;
  int jwg = jb * 4 + cg;             // 16-col group 0..63
  int nb  = jwg * 48;
  int m0  = mg * 16;
  int j   = jwg * 16 + jl;
  const bhalf* Bp  = dir ? A.packB : A.packF;
  const bhalf* tab = dir ? A.tabB  : A.tabF;
  const float* bhh = dir ? A.bhhB  : A.bhhF;
  bhalf* hpp0 = dir ? A.hb0B : A.hb0F;
  bhalf* hpp1 = dir ? A.hb1B : A.hb1F;
  unsigned* myE = A.barE + (size_t)(dir * 8 + mg) * 32;
  float bhr = bhh[j], bhz = bhh[HID + j], bhn = bhh[2 * HID + j];

  // wave's weight K-half slice: 3 gates x 16 chunks x 16B = 192 VGPR
  bf16x8 breg[3][16];
#pragma unroll
  for (int g = 0; g < 3; ++g) {
    const bhalf* bp = Bp + (size_t)(nb + g * 16 + jl) * HID + kbase + q * 8;
#pragma unroll
    for (int i = 0; i < 16; ++i) breg[g][i] = *(const bf16x8*)(bp + i * 32);
  }

  // zero my (m,j) slice of ping buffer 0 (coherent); fp32 h master in hreg
  float hreg[4] = {};
  if (!kh) {
#pragma unroll
    for (int reg = 0; reg < 4; ++reg)
      coh_st_h(&hpp0[(size_t)(m0 + q * 4 + reg) * HID + j], 0.f);
  }
  gbar(A.barF, NBLK);

  // ===== encoder: 64 steps =====
  unsigned et = 0;
  for (int t = 0; t < TIN; ++t) {
    const bhalf* hcur = (t & 1) ? hpp1 : hpp0;
    bhalf*       hnxt = (t & 1) ? hpp0 : hpp1;
    const bhalf* pa = hcur + (size_t)(m0 + jl) * HID + kbase + q * 8;
    // prefetch tokens early (independent of h)
    int tok[4];
    if (!kh) {
#pragma unroll
      for (int reg = 0; reg < 4; ++reg)
        tok[reg] = A.in_text[(m0 + q * 4 + reg) * TIN + t];
    }
    f32x4 acc[3] = {};
#pragma unroll
    for (int i = 0; i < 16; ++i) {
      bf16x8 a0 = coh_ld16(pa + i * 32);
      acc[0] = MFMA(a0, breg[0][i], acc[0]);
      acc[1] = MFMA(a0, breg[1][i], acc[1]);
      acc[2] = MFMA(a0, breg[2][i], acc[2]);
    }
    if (kh) {
      red[cg][0][l] = acc[0]; red[cg][1][l] = acc[1]; red[cg][2][l] = acc[2];
    }
    __syncthreads();
    if (!kh) {
      acc[0] += red[cg][0][l]; acc[1] += red[cg][1][l]; acc[2] += red[cg][2][l];
#pragma unroll
      for (int reg = 0; reg < 4; ++reg) {
        int m = m0 + q * 4 + reg;
        const bhalf* gi = tab + (size_t)tok[reg] * G3;
        float r = sigm(__bfloat162float(gi[j]) + acc[0][reg] + bhr);
        float z = sigm(__bfloat162float(gi[HID + j]) + acc[1][reg] + bhz);
        float n = tanh_f(__bfloat162float(gi[2 * HID + j]) + r * (acc[2][reg] + bhn));
        float hv = (1.f - z) * n + z * hreg[reg];
        hreg[reg] = hv;
        coh_st_h(&hnxt[(size_t)m * HID + j], hv);
      }
    }
    et += 16;
    if (t < TIN - 1) gbar(myE, et);  // domain barrier: 16 blocks of (dir,mg)
  }

  // ===== handoff: final fp32 h -> hfin (coherent); full barrier =====
  if (!kh) {
    float* hfin = dir ? A.hfinB : A.hfinF;
#pragma unroll
    for (int reg = 0; reg < 4; ++reg)
      coh_st_f(&hfin[(size_t)(m0 + q * 4 + reg) * HID + j], hreg[reg]);
  }
  gbar(A.barF, 2 * NBLK);

  if (bid >= 128) return;   // decoder uses 128 blocks

  // ===== decoder mapping: bid = mg2*16 + jb2 =====
  int mg2 = bid >> 4;
  int jb2 = bid & 15;
  int jwg2 = jb2 * 4 + cg;
  int nb2 = jwg2 * 48;
  int m20 = mg2 * 16;
  int j2  = jwg2 * 16 + jl;
  unsigned* myD = A.barD + (size_t)mg2 * 32;
  float b2r = A.bhhD[j2], b2z = A.bhhD[HID + j2], b2n = A.bhhD[2 * HID + j2];
#pragma unroll
  for (int g = 0; g < 3; ++g) {
    const bhalf* bp = A.packD + (size_t)(nb2 + g * 16 + jl) * HID + kbase + q * 8;
#pragma unroll
    for (int i = 0; i < 16; ++i) breg[g][i] = *(const bf16x8*)(bp + i * 32);
  }
  float hreg4[4];
  if (!kh) {
#pragma unroll
    for (int reg = 0; reg < 4; ++reg) {
      int m = m20 + q * 4 + reg;
      float s = coh_ld_f(&A.hfinF[(size_t)m * HID + j2]) +
                coh_ld_f(&A.hfinB[(size_t)m * HID + j2]);
      hreg4[reg] = s;
      coh_st_h(&A.h0bf[(size_t)m * HID + j2], s);
    }
  }
  unsigned dt = 16;
  gbar(myD, dt);

  // ===== decoder: 90 steps; bf16 h written straight into hs slab =====
  for (int t = 0; t < TOUT; ++t) {
    const bhalf* Asrc = t ? (A.hs + (size_t)(t - 1) * BH) : A.h0bf;
    const bhalf* pa = Asrc + (size_t)(m20 + jl) * HID + kbase + q * 8;
    int pt = t ? t - 1 : 0;
    int tok[4];
    if (!kh) {
#pragma unroll
      for (int reg = 0; reg < 4; ++reg)
        tok[reg] = A.poses[(m20 + q * 4 + reg) * TOUT + pt];
    }
    f32x4 acc[3] = {};
#pragma unroll
    for (int i = 0; i < 16; ++i) {
      bf16x8 a0 = coh_ld16(pa + i * 32);
      acc[0] = MFMA(a0, breg[0][i], acc[0]);
      acc[1] = MFMA(a0, breg[1][i], acc[1]);
      acc[2] = MFMA(a0, breg[2][i], acc[2]);
    }
    if (kh) {
      red[cg][0][l] = acc[0]; red[cg][1][l] = acc[1]; red[cg][2][l] = acc[2];
    }
    __syncthreads();
    if (!kh) {
      acc[0] += red[cg][0][l]; acc[1] += red[cg][1][l]; acc[2] += red[cg][2][l];
      bhalf* hout = A.hs + (size_t)t * BH;
#pragma unroll
      for (int reg = 0; reg < 4; ++reg) {
        int m = m20 + q * 4 + reg;
        const bhalf* gi = A.tabD + (size_t)tok[reg] * G3;
        float r = sigm(__bfloat162float(gi[j2]) + acc[0][reg] + b2r);
        float z = sigm(__bfloat162float(gi[HID + j2]) + acc[1][reg] + b2z);
        float n = tanh_f(__bfloat162float(gi[2 * HID + j2]) + r * (acc[2][reg] + b2n));
        float hv = (1.f - z) * n + z * hreg4[reg];
        hreg4[reg] = hv;
        coh_st_h(&hout[(size_t)m * HID + j2], hv);
      }
    }
    dt += 16;
    if (t < TOUT - 1) gbar(myD, dt);
  }
}

extern "C" void kernel_launch(void* const* d_in, const int* in_sizes, int n_in,
                              void* d_out, int out_size, void* d_ws, size_t ws_size,
                              hipStream_t stream) {
  const float* enc_emb   = (const float*)d_in[0];
  const float* enc_Wih_f = (const float*)d_in[1];
  const float* enc_Whh_f = (const float*)d_in[2];
  const float* enc_bih_f = (const float*)d_in[3];
  const float* enc_bhh_f = (const float*)d_in[4];
  const float* enc_Wih_b = (const float*)d_in[5];
  const float* enc_Whh_b = (const float*)d_in[6];
  const float* enc_bih_b = (const float*)d_in[7];
  const float* enc_bhh_b = (const float*)d_in[8];
  const float* dec_emb   = (const float*)d_in[9];
  const float* dec_Wih   = (const float*)d_in[10];
  const float* dec_Whh   = (const float*)d_in[11];
  const float* dec_bih   = (const float*)d_in[12];
  const float* dec_bhh   = (const float*)d_in[13];
  const float* fc_W      = (const float*)d_in[14];
  const float* fc_b      = (const float*)d_in[15];
  const int*   in_text   = (const int*)d_in[16];
  const int*   poses     = (const int*)d_in[18];
  float* out = (float*)d_out;

  char* p = (char*)d_ws;
  auto alloc = [&](size_t n) { char* r = p; p += (n + 255) & ~(size_t)255; return r; };
  bhalf* tabF  = (bhalf*)alloc((size_t)VOCAB * G3 * 2);
  bhalf* tabB  = (bhalf*)alloc((size_t)VOCAB * G3 * 2);
  bhalf* tabD  = (bhalf*)alloc((size_t)POSE * G3 * 2);
  bhalf* hb0F  = (bhalf*)alloc(BH * 2);
  bhalf* hb1F  = (bhalf*)alloc(BH * 2);
  bhalf* hb0B  = (bhalf*)alloc(BH * 2);
  bhalf* hb1B  = (bhalf*)alloc(BH * 2);
  float* hfinF = (float*)alloc(BH * 4);
  float* hfinB = (float*)alloc(BH * 4);
  bhalf* h0bf  = (bhalf*)alloc(BH * 2);
  bhalf* hs    = (bhalf*)alloc((size_t)TOUT * BH * 2);
  bhalf* embbf = (bhalf*)alloc((size_t)VOCAB * EMBP * 2);
  bhalf* wihF  = (bhalf*)alloc((size_t)G3 * EMBP * 2);
  bhalf* wihB  = (bhalf*)alloc((size_t)G3 * EMBP * 2);
  bhalf* dembbf= (bhalf*)alloc((size_t)POSE * HID * 2);
  bhalf* dwih  = (bhalf*)alloc((size_t)G3 * HID * 2);
  bhalf* fcw   = (bhalf*)alloc((size_t)544 * HID * 2);
  bhalf* packF = (bhalf*)alloc((size_t)G3 * HID * 2);
  bhalf* packB = (bhalf*)alloc((size_t)G3 * HID * 2);
  bhalf* packD = (bhalf*)alloc((size_t)G3 * HID * 2);
  unsigned* bars = (unsigned*)alloc(4096);
  unsigned* barF = bars;
  unsigned* barE = bars + 32;
  unsigned* barD = bars + 32 + 16 * 32;

  auto cgrid = [](int total) { return dim3((total + 255) / 256); };

  // one-off conversions / packing (+ barrier counters zero)
  k_zerobar<<<dim3(4), 256, 0, stream>>>(bars);
  k_convert<<<cgrid(VOCAB * EMBP), 256, 0, stream>>>(enc_emb, embbf, VOCAB, EMB, EMBP, VOCAB * EMBP);
  k_convert<<<cgrid(G3 * EMBP),   256, 0, stream>>>(enc_Wih_f, wihF, G3, EMB, EMBP, G3 * EMBP);
  k_convert<<<cgrid(G3 * EMBP),   256, 0, stream>>>(enc_Wih_b, wihB, G3, EMB, EMBP, G3 * EMBP);
  k_convert<<<cgrid(POSE * HID),  256, 0, stream>>>(dec_emb, dembbf, POSE, HID, HID, POSE * HID);
  k_convert<<<cgrid(G3 * HID),    256, 0, stream>>>(dec_Wih, dwih, G3, HID, HID, G3 * HID);
  k_convert<<<cgrid(544 * HID),   256, 0, stream>>>(fc_W, fcw, POSE, HID, HID, 544 * HID);
  k_pack<<<cgrid(G3 * HID), 256, 0, stream>>>(enc_Whh_f, packF);
  k_pack<<<cgrid(G3 * HID), 256, 0, stream>>>(enc_Whh_b, packB);
  k_pack<<<cgrid(G3 * HID), 256, 0, stream>>>(dec_Whh, packD);

  // gi tables (bf16, bih folded)
  k_gemm<1><<<dim3(96, 31), 256, 0, stream>>>(embbf, wihF, enc_bih_f, nullptr, tabF, VOCAB, EMBP, G3);
  k_gemm<1><<<dim3(96, 31), 256, 0, stream>>>(embbf, wihB, enc_bih_b, nullptr, tabB, VOCAB, EMBP, G3);
  k_gemm<1><<<dim3(96, 5),  256, 0, stream>>>(dembbf, dwih, dec_bih, nullptr, tabD, POSE, HID, G3);

  // persistent enc+dec
  SeqArgs sa;
  sa.packF = packF; sa.packB = packB; sa.packD = packD;
  sa.tabF = tabF; sa.tabB = tabB; sa.tabD = tabD;
  sa.bhhF = enc_bhh_f; sa.bhhB = enc_bhh_b; sa.bhhD = dec_bhh;
  sa.in_text = in_text; sa.poses = poses;
  sa.hb0F = hb0F; sa.hb1F = hb1F; sa.hb0B = hb0B; sa.hb1B = hb1B;
  sa.hfinF = hfinF; sa.hfinB = hfinB; sa.h0bf = h0bf; sa.hs = hs;
  sa.barF = barF; sa.barE = barE; sa.barD = barD;
  k_seq<<<dim3(NBLK), dim3(512), 0, stream>>>(sa);

  // output projection
  k_gemm<0><<<dim3(17, 90), 256, 0, stream>>>(hs, fcw, fc_b, out, nullptr, TOUT * BATCH, HID, POSE);
}

// Round 7
// 2334.287 us; speedup vs baseline: 2.1641x; 1.1320x over previous
//
#include <hip/hip_runtime.h>
#include <hip/hip_bf16.h>

#define HID   1024
#define G3    3072
#define EMB   300
#define EMBP  320      // K padded to multiple of 32
#define VOCAB 3863
#define POSE  514
#define BATCH 128
#define TIN   64
#define TOUT  90
#define BH    (BATCH * HID)
#define NBLK  256

typedef __bf16 bf16x8 __attribute__((ext_vector_type(8)));
typedef float  f32x4  __attribute__((ext_vector_type(4)));
typedef __hip_bfloat16 bhalf;
typedef unsigned long long u64;

#define MFMA(a,b,c) __builtin_amdgcn_mfma_f32_16x16x32_bf16((a),(b),(c),0,0,0)

__device__ __forceinline__ float sigm(float x) { return 1.f / (1.f + __expf(-x)); }
__device__ __forceinline__ float tanh_f(float x) { return 1.f - 2.f / (__expf(2.f * x) + 1.f); }

// ---- agent-coherent helpers (sc0 sc1): bypass stale L1/L2 for h exchange ----
// proven in round 6 (passed, absmax unchanged vs fenced version)
__device__ __forceinline__ bf16x8 coh_ld16(const bhalf* p) {
  union { u64 u[2]; bf16x8 v; } r;
  r.u[0] = __hip_atomic_load((const u64*)p,     __ATOMIC_RELAXED, __HIP_MEMORY_SCOPE_AGENT);
  r.u[1] = __hip_atomic_load((const u64*)p + 1, __ATOMIC_RELAXED, __HIP_MEMORY_SCOPE_AGENT);
  return r.v;
}
__device__ __forceinline__ void coh_st_h(bhalf* p, float v) {
  union { bhalf b; unsigned short s; } u;
  u.b = __float2bfloat16(v);
  __hip_atomic_store((unsigned short*)p, u.s, __ATOMIC_RELAXED, __HIP_MEMORY_SCOPE_AGENT);
}
__device__ __forceinline__ void coh_st_f(float* p, float v) {
  __hip_atomic_store(p, v, __ATOMIC_RELAXED, __HIP_MEMORY_SCOPE_AGENT);
}
__device__ __forceinline__ float coh_ld_f(const float* p) {
  return __hip_atomic_load((const float*)p, __ATOMIC_RELAXED, __HIP_MEMORY_SCOPE_AGENT);
}

// ---- grid barrier, no cache-invalidating fence (h goes via coherent ops) ----
__device__ __forceinline__ void gbar(unsigned* bar, unsigned tgt) {
  __syncthreads();
  if (threadIdx.x == 0) {
    __hip_atomic_fetch_add(bar, 1u, __ATOMIC_RELEASE, __HIP_MEMORY_SCOPE_AGENT);
    while (__hip_atomic_load(bar, __ATOMIC_RELAXED, __HIP_MEMORY_SCOPE_AGENT) < tgt)
      __builtin_amdgcn_s_sleep(1);
  }
  __syncthreads();
  asm volatile("" ::: "memory");
}

__global__ void k_zerobar(unsigned* p) {
  int i = blockIdx.x * 256 + threadIdx.x;
  if (i < 1024)
    __hip_atomic_store(p + i, 0u, __ATOMIC_RELAXED, __HIP_MEMORY_SCOPE_AGENT);
}

// ---------- fp32 -> bf16 conversion with zero padding ----------
__global__ __launch_bounds__(256) void k_convert(const float* __restrict__ src,
        bhalf* __restrict__ dst, int rows_in, int cols_in, int cols_out, int total) {
  int i = blockIdx.x * 256 + threadIdx.x;
  if (i >= total) return;
  int r = i / cols_out, c = i - r * cols_out;
  float v = (r < rows_in && c < cols_in) ? src[(size_t)r * cols_in + c] : 0.f;
  dst[i] = __float2bfloat16(v);
}

// ---------- pack Whh [3H][H] -> [(j>>4)*48 + g*16 + (j&15)][k] bf16 ----------
__global__ __launch_bounds__(256) void k_pack(const float* __restrict__ whh,
                                              bhalf* __restrict__ dst) {
  int i = blockIdx.x * 256 + threadIdx.x;
  if (i >= G3 * HID) return;
  int k  = i & (HID - 1);
  int rp = i >> 10;
  int jg  = rp / 48;
  int rem = rp - jg * 48;
  int g = rem >> 4, jl = rem & 15;
  int j = (jg << 4) + jl;
  dst[i] = __float2bfloat16(whh[(size_t)((g << 10) + j) * HID + k]);
}

// ---------- MFMA GEMM-NT, XCD-chunked swizzle; OUTBF: bf16 C vs f32 C ----------
template<int OUTBF>
__global__ __launch_bounds__(256) void k_gemm(
    const bhalf* __restrict__ A, const bhalf* __restrict__ B,
    const float* __restrict__ bias, float* __restrict__ Cf, bhalf* __restrict__ Cb,
    int M, int K, int Nstore) {
  int gx = gridDim.x;
  int nwg = gx * gridDim.y;
  int orig = blockIdx.y * gx + blockIdx.x;
  int xcd = orig & 7, sl = orig >> 3;
  int qq = nwg >> 3, rr = nwg & 7;
  int nbid = (xcd < rr ? xcd * (qq + 1) : rr * (qq + 1) + (xcd - rr) * qq) + sl;
  int bx = nbid % gx, by = nbid / gx;

  int tid = threadIdx.x;
  int l = tid & 63, w = tid >> 6;
  int q = l >> 4, jl = l & 15;
  int n0 = bx * 32;
  int m0 = by * 128 + w * 32;
  int ar0 = m0 + jl;       if (ar0 >= M) ar0 = M - 1;
  int ar1 = m0 + 16 + jl;  if (ar1 >= M) ar1 = M - 1;
  const bhalf* pa0 = A + (size_t)ar0 * K + q * 8;
  const bhalf* pa1 = A + (size_t)ar1 * K + q * 8;
  const bhalf* pb0 = B + (size_t)(n0 + jl) * K + q * 8;
  const bhalf* pb1 = B + (size_t)(n0 + 16 + jl) * K + q * 8;
  f32x4 acc[2][2] = {};
#pragma unroll 4
  for (int kc = 0; kc < K; kc += 32) {
    bf16x8 a0 = *(const bf16x8*)(pa0 + kc);
    bf16x8 a1 = *(const bf16x8*)(pa1 + kc);
    bf16x8 b0 = *(const bf16x8*)(pb0 + kc);
    bf16x8 b1 = *(const bf16x8*)(pb1 + kc);
    acc[0][0] = MFMA(a0, b0, acc[0][0]);
    acc[0][1] = MFMA(a0, b1, acc[0][1]);
    acc[1][0] = MFMA(a1, b0, acc[1][0]);
    acc[1][1] = MFMA(a1, b1, acc[1][1]);
  }
#pragma unroll
  for (int sub = 0; sub < 2; ++sub)
#pragma unroll
    for (int ns = 0; ns < 2; ++ns)
#pragma unroll
      for (int reg = 0; reg < 4; ++reg) {
        int row = m0 + sub * 16 + q * 4 + reg;
        int col = n0 + ns * 16 + jl;
        if (row < M && col < Nstore) {
          float v = acc[sub][ns][reg] + bias[col];
          if (OUTBF) Cb[(size_t)row * Nstore + col] = __float2bfloat16(v);
          else       Cf[(size_t)row * Nstore + col] = v;
        }
      }
}

// ---------- persistent kernel ----------
// 256 blocks x 256 thr. Block owns 16 j-cols; weights (48 rows x 1024 K bf16 =
// 96KB) live in XOR-swizzled LDS (un-spillable). 4 waves split K (256 each),
// partials reduced via 36KB LDS slab. Domain = 64 blocks covering all 3072
// gate-rows for its batch-row group. h exchanged via coherent ld/st.
struct SeqArgs {
  const bhalf *packF, *packB, *packD;
  const bhalf *tabF, *tabB, *tabD;   // bf16 gi tables (bih folded)
  const float *bhhF, *bhhB, *bhhD;
  const int *in_text, *poses;
  bhalf *hb0F, *hb1F, *hb0B, *hb1B;  // enc bf16 h ping-pong, per dir
  float *hfinF, *hfinB;              // enc final fp32 h
  bhalf *h0bf;                       // dec_h0 bf16
  bhalf *hs;                         // [90][128][1024] decoder hidden chain
  unsigned *barF, *barE, *barD;      // full / encoder-domain / decoder-domain
};

__device__ __forceinline__ void load_w(char* wlds, const bhalf* wsrc, int tid) {
  // 48 rows x 1024 cols bf16, 16B chunks, XOR-swizzle byte ^= (row&7)<<4
  for (int it = tid; it < 6144; it += 256) {
    int row = it >> 7, c8 = it & 127;
    int off = (row * 1024 + c8 * 8) * 2;
    *(bf16x8*)(wlds + (off ^ ((row & 7) << 4))) =
        *(const bf16x8*)(wsrc + row * 1024 + c8 * 8);
  }
}

__device__ __forceinline__ bf16x8 ldsB(const char* wlds, int row, int kcol) {
  int off = (row * 1024 + kcol) * 2;
  return *(const bf16x8*)(wlds + (off ^ ((row & 7) << 4)));
}

__global__ __launch_bounds__(256) void k_seq(SeqArgs A) {
  __shared__ char  wlds[96 * 1024];
  __shared__ f32x4 part[3][4][3][64];   // writer-slot, m-tile, gate, lane
  int tid = threadIdx.x;
  int l = tid & 63, w = tid >> 6;       // wave 0..3 = K-quarter
  int q = l >> 4, jl = l & 15;
  int bid = blockIdx.x;
  int kbase = w * 256;

  // ===== encoder mapping: bid = dir*128 + mg*64 + jb =====
  int dir = bid >> 7;
  int mg  = (bid >> 6) & 1;
  int dom = bid >> 6;                   // 0..3
  int jb  = bid & 63;
  int m0  = mg * 64;
  int j   = jb * 16 + jl;
  const bhalf* Bp  = dir ? A.packB : A.packF;
  const bhalf* tab = dir ? A.tabB  : A.tabF;
  const float* bhh = dir ? A.bhhB  : A.bhhF;
  bhalf* hpp0 = dir ? A.hb0B : A.hb0F;
  bhalf* hpp1 = dir ? A.hb1B : A.hb1F;
  unsigned* myE = A.barE + (size_t)dom * 32;
  float bhr = bhh[j], bhz = bhh[HID + j], bhn = bhh[2 * HID + j];

  load_w(wlds, Bp + (size_t)jb * 48 * 1024, tid);

  // zero owner slice of ping buffer 0; fp32 h master in hreg (owner wave = w)
  float hreg[4] = {};
#pragma unroll
  for (int reg = 0; reg < 4; ++reg)
    coh_st_h(&hpp0[(size_t)(m0 + w * 16 + q * 4 + reg) * HID + j], 0.f);
  gbar(A.barF, NBLK);   // also covers LDS weight visibility (syncthreads inside)

  // ===== encoder: 64 steps =====
  unsigned et = 0;
  for (int t = 0; t < TIN; ++t) {
    const bhalf* hcur = (t & 1) ? hpp1 : hpp0;
    bhalf*       hnxt = (t & 1) ? hpp0 : hpp1;
    // early-issue tok -> gi chain (independent of h)
    float gir[4], giz[4], gin[4];
#pragma unroll
    for (int reg = 0; reg < 4; ++reg) {
      int m = m0 + w * 16 + q * 4 + reg;
      int tok = A.in_text[m * TIN + t];
      const bhalf* gi = tab + (size_t)tok * G3;
      gir[reg] = __bfloat162float(gi[j]);
      giz[reg] = __bfloat162float(gi[HID + j]);
      gin[reg] = __bfloat162float(gi[2 * HID + j]);
    }
    const bhalf* paBase = hcur + (size_t)(m0 + jl) * HID + kbase + q * 8;
    f32x4 acc[4][3] = {};
#pragma unroll
    for (int i = 0; i < 8; ++i) {
      bf16x8 b0 = ldsB(wlds,      jl, kbase + i * 32 + q * 8);
      bf16x8 b1 = ldsB(wlds, 16 + jl, kbase + i * 32 + q * 8);
      bf16x8 b2 = ldsB(wlds, 32 + jl, kbase + i * 32 + q * 8);
#pragma unroll
      for (int mt = 0; mt < 4; ++mt) {
        bf16x8 a0 = coh_ld16(paBase + mt * 16 * HID + i * 32);
        acc[mt][0] = MFMA(a0, b0, acc[mt][0]);
        acc[mt][1] = MFMA(a0, b1, acc[mt][1]);
        acc[mt][2] = MFMA(a0, b2, acc[mt][2]);
      }
    }
    // write partials for non-owned m-tiles (static mt indices; rule #20 safe)
#pragma unroll
    for (int mt = 0; mt < 4; ++mt) {
      if (mt != w) {
        int wi = w - (w > mt ? 1 : 0);
        part[wi][mt][0][l] = acc[mt][0];
        part[wi][mt][1][l] = acc[mt][1];
        part[wi][mt][2][l] = acc[mt][2];
      }
    }
    __syncthreads();
    // owner wave (mt == w): reduce + gates + coherent store
    f32x4 f0 = {}, f1 = {}, f2 = {};
#pragma unroll
    for (int mt = 0; mt < 4; ++mt)
      if (mt == w) { f0 = acc[mt][0]; f1 = acc[mt][1]; f2 = acc[mt][2]; }
#pragma unroll
    for (int s = 0; s < 3; ++s) {
      f0 += part[s][w][0][l]; f1 += part[s][w][1][l]; f2 += part[s][w][2][l];
    }
#pragma unroll
    for (int reg = 0; reg < 4; ++reg) {
      float r = sigm(gir[reg] + f0[reg] + bhr);
      float z = sigm(giz[reg] + f1[reg] + bhz);
      float n = tanh_f(gin[reg] + r * (f2[reg] + bhn));
      float hv = (1.f - z) * n + z * hreg[reg];
      hreg[reg] = hv;
      coh_st_h(&hnxt[(size_t)(m0 + w * 16 + q * 4 + reg) * HID + j], hv);
    }
    et += 64;
    if (t < TIN - 1) gbar(myE, et);
  }

  // ===== handoff: final fp32 h -> hfin; full barrier =====
  {
    float* hfin = dir ? A.hfinB : A.hfinF;
#pragma unroll
    for (int reg = 0; reg < 4; ++reg)
      coh_st_f(&hfin[(size_t)(m0 + w * 16 + q * 4 + reg) * HID + j], hreg[reg]);
  }
  gbar(A.barF, 2 * NBLK);

  // ===== decoder mapping: bid = dom2*64 + jb2; 32 rows, 2 m-tiles =====
  int dom2 = bid >> 6;
  int jb2  = bid & 63;
  int m20  = dom2 * 32;
  int j2   = jb2 * 16 + jl;
  unsigned* myD = A.barD + (size_t)dom2 * 32;
  float b2r = A.bhhD[j2], b2z = A.bhhD[HID + j2], b2n = A.bhhD[2 * HID + j2];

  load_w(wlds, A.packD + (size_t)jb2 * 48 * 1024, tid);

  float hreg4[4];
  if (w < 2) {
#pragma unroll
    for (int reg = 0; reg < 4; ++reg) {
      int m = m20 + w * 16 + q * 4 + reg;
      float s = coh_ld_f(&A.hfinF[(size_t)m * HID + j2]) +
                coh_ld_f(&A.hfinB[(size_t)m * HID + j2]);
      hreg4[reg] = s;
      coh_st_h(&A.h0bf[(size_t)m * HID + j2], s);
    }
  }
  unsigned dt = 64;
  gbar(myD, dt);   // h0bf + decoder LDS weights visible

  // ===== decoder: 90 steps; bf16 h written straight into hs slab =====
  for (int t = 0; t < TOUT; ++t) {
    const bhalf* Asrc = t ? (A.hs + (size_t)(t - 1) * BH) : A.h0bf;
    int pt = t ? t - 1 : 0;
    float gir[4], giz[4], gin[4];
    if (w < 2) {
#pragma unroll
      for (int reg = 0; reg < 4; ++reg) {
        int m = m20 + w * 16 + q * 4 + reg;
        int tok = A.poses[m * TOUT + pt];
        const bhalf* gi = A.tabD + (size_t)tok * G3;
        gir[reg] = __bfloat162float(gi[j2]);
        giz[reg] = __bfloat162float(gi[HID + j2]);
        gin[reg] = __bfloat162float(gi[2 * HID + j2]);
      }
    }
    const bhalf* paBase = Asrc + (size_t)(m20 + jl) * HID + kbase + q * 8;
    f32x4 acc[2][3] = {};
#pragma unroll
    for (int i = 0; i < 8; ++i) {
      bf16x8 b0 = ldsB(wlds,      jl, kbase + i * 32 + q * 8);
      bf16x8 b1 = ldsB(wlds, 16 + jl, kbase + i * 32 + q * 8);
      bf16x8 b2 = ldsB(wlds, 32 + jl, kbase + i * 32 + q * 8);
#pragma unroll
      for (int mt = 0; mt < 2; ++mt) {
        bf16x8 a0 = coh_ld16(paBase + mt * 16 * HID + i * 32);
        acc[mt][0] = MFMA(a0, b0, acc[mt][0]);
        acc[mt][1] = MFMA(a0, b1, acc[mt][1]);
        acc[mt][2] = MFMA(a0, b2, acc[mt][2]);
      }
    }
#pragma unroll
    for (int mt = 0; mt < 2; ++mt) {
      if (mt != w) {
        int wi = w - (w > mt ? 1 : 0);
        part[wi][mt][0][l] = acc[mt][0];
        part[wi][mt][1][l] = acc[mt][1];
        part[wi][mt][2][l] = acc[mt][2];
      }
    }
    __syncthreads();
    if (w < 2) {
      f32x4 f0 = {}, f1 = {}, f2 = {};
#pragma unroll
      for (int mt = 0; mt < 2; ++mt)
        if (mt == w) { f0 = acc[mt][0]; f1 = acc[mt][1]; f2 = acc[mt][2]; }
#pragma unroll
      for (int s = 0; s < 3; ++s) {
        f0 += part[s][w][0][l]; f1 += part[s][w][1][l]; f2 += part[s][w][2][l];
      }
      bhalf* hout = A.hs + (size_t)t * BH;
#pragma unroll
      for (int reg = 0; reg < 4; ++reg) {
        float r = sigm(gir[reg] + f0[reg] + b2r);
        float z = sigm(giz[reg] + f1[reg] + b2z);
        float n = tanh_f(gin[reg] + r * (f2[reg] + b2n));
        float hv = (1.f - z) * n + z * hreg4[reg];
        hreg4[reg] = hv;
        coh_st_h(&hout[(size_t)(m20 + w * 16 + q * 4 + reg) * HID + j2], hv);
      }
    }
    dt += 64;
    if (t < TOUT - 1) gbar(myD, dt);
  }
}

extern "C" void kernel_launch(void* const* d_in, const int* in_sizes, int n_in,
                              void* d_out, int out_size, void* d_ws, size_t ws_size,
                              hipStream_t stream) {
  const float* enc_emb   = (const float*)d_in[0];
  const float* enc_Wih_f = (const float*)d_in[1];
  const float* enc_Whh_f = (const float*)d_in[2];
  const float* enc_bih_f = (const float*)d_in[3];
  const float* enc_bhh_f = (const float*)d_in[4];
  const float* enc_Wih_b = (const float*)d_in[5];
  const float* enc_Whh_b = (const float*)d_in[6];
  const float* enc_bih_b = (const float*)d_in[7];
  const float* enc_bhh_b = (const float*)d_in[8];
  const float* dec_emb   = (const float*)d_in[9];
  const float* dec_Wih   = (const float*)d_in[10];
  const float* dec_Whh   = (const float*)d_in[11];
  const float* dec_bih   = (const float*)d_in[12];
  const float* dec_bhh   = (const float*)d_in[13];
  const float* fc_W      = (const float*)d_in[14];
  const float* fc_b      = (const float*)d_in[15];
  const int*   in_text   = (const int*)d_in[16];
  const int*   poses     = (const int*)d_in[18];
  float* out = (float*)d_out;

  char* p = (char*)d_ws;
  auto alloc = [&](size_t n) { char* r = p; p += (n + 255) & ~(size_t)255; return r; };
  bhalf* tabF  = (bhalf*)alloc((size_t)VOCAB * G3 * 2);
  bhalf* tabB  = (bhalf*)alloc((size_t)VOCAB * G3 * 2);
  bhalf* tabD  = (bhalf*)alloc((size_t)POSE * G3 * 2);
  bhalf* hb0F  = (bhalf*)alloc(BH * 2);
  bhalf* hb1F  = (bhalf*)alloc(BH * 2);
  bhalf* hb0B  = (bhalf*)alloc(BH * 2);
  bhalf* hb1B  = (bhalf*)alloc(BH * 2);
  float* hfinF = (float*)alloc(BH * 4);
  float* hfinB = (float*)alloc(BH * 4);
  bhalf* h0bf  = (bhalf*)alloc(BH * 2);
  bhalf* hs    = (bhalf*)alloc((size_t)TOUT * BH * 2);
  bhalf* embbf = (bhalf*)alloc((size_t)VOCAB * EMBP * 2);
  bhalf* wihF  = (bhalf*)alloc((size_t)G3 * EMBP * 2);
  bhalf* wihB  = (bhalf*)alloc((size_t)G3 * EMBP * 2);
  bhalf* dembbf= (bhalf*)alloc((size_t)POSE * HID * 2);
  bhalf* dwih  = (bhalf*)alloc((size_t)G3 * HID * 2);
  bhalf* fcw   = (bhalf*)alloc((size_t)544 * HID * 2);
  bhalf* packF = (bhalf*)alloc((size_t)G3 * HID * 2);
  bhalf* packB = (bhalf*)alloc((size_t)G3 * HID * 2);
  bhalf* packD = (bhalf*)alloc((size_t)G3 * HID * 2);
  unsigned* bars = (unsigned*)alloc(4096);
  unsigned* barF = bars;               // 1 counter (padded)
  unsigned* barE = bars + 32;          // 4 domain counters x 32 uints
  unsigned* barD = bars + 32 + 4 * 32; // 4 domain counters

  auto cgrid = [](int total) { return dim3((total + 255) / 256); };

  // one-off conversions / packing (+ barrier counters zero)
  k_zerobar<<<dim3(4), 256, 0, stream>>>(bars);
  k_convert<<<cgrid(VOCAB * EMBP), 256, 0, stream>>>(enc_emb, embbf, VOCAB, EMB, EMBP, VOCAB * EMBP);
  k_convert<<<cgrid(G3 * EMBP),   256, 0, stream>>>(enc_Wih_f, wihF, G3, EMB, EMBP, G3 * EMBP);
  k_convert<<<cgrid(G3 * EMBP),   256, 0, stream>>>(enc_Wih_b, wihB, G3, EMB, EMBP, G3 * EMBP);
  k_convert<<<cgrid(POSE * HID),  256, 0, stream>>>(dec_emb, dembbf, POSE, HID, HID, POSE * HID);
  k_convert<<<cgrid(G3 * HID),    256, 0, stream>>>(dec_Wih, dwih, G3, HID, HID, G3 * HID);
  k_convert<<<cgrid(544 * HID),   256, 0, stream>>>(fc_W, fcw, POSE, HID, HID, 544 * HID);
  k_pack<<<cgrid(G3 * HID), 256, 0, stream>>>(enc_Whh_f, packF);
  k_pack<<<cgrid(G3 * HID), 256, 0, stream>>>(enc_Whh_b, packB);
  k_pack<<<cgrid(G3 * HID), 256, 0, stream>>>(dec_Whh, packD);

  // gi tables (bf16, bih folded)
  k_gemm<1><<<dim3(96, 31), 256, 0, stream>>>(embbf, wihF, enc_bih_f, nullptr, tabF, VOCAB, EMBP, G3);
  k_gemm<1><<<dim3(96, 31), 256, 0, stream>>>(embbf, wihB, enc_bih_b, nullptr, tabB, VOCAB, EMBP, G3);
  k_gemm<1><<<dim3(96, 5),  256, 0, stream>>>(dembbf, dwih, dec_bih, nullptr, tabD, POSE, HID, G3);

  // persistent enc+dec
  SeqArgs sa;
  sa.packF = packF; sa.packB = packB; sa.packD = packD;
  sa.tabF = tabF; sa.tabB = tabB; sa.tabD = tabD;
  sa.bhhF = enc_bhh_f; sa.bhhB = enc_bhh_b; sa.bhhD = dec_bhh;
  sa.in_text = in_text; sa.poses = poses;
  sa.hb0F = hb0F; sa.hb1F = hb1F; sa.hb0B = hb0B; sa.hb1B = hb1B;
  sa.hfinF = hfinF; sa.hfinB = hfinB; sa.h0bf = h0bf; sa.hs = hs;
  sa.barF = barF; sa.barE = barE; sa.barD = barD;
  k_seq<<<dim3(NBLK), dim3(256), 0, stream>>>(sa);

  // output projection
  k_gemm<0><<<dim3(17, 90), 256, 0, stream>>>(hs, fcw, fc_b, out, nullptr, TOUT * BATCH, HID, POSE);
}

// Round 8
// 1873.655 us; speedup vs baseline: 2.6962x; 1.2458x over previous
//
#include <hip/hip_runtime.h>
#include <hip/hip_bf16.h>

#define HID   1024
#define G3    3072
#define EMB   300
#define EMBP  320      // K padded to multiple of 32
#define VOCAB 3863
#define POSE  514
#define BATCH 128
#define TIN   64
#define TOUT  90
#define BH    (BATCH * HID)
#define NBLK  256

typedef __bf16 bf16x8 __attribute__((ext_vector_type(8)));
typedef float  f32x4  __attribute__((ext_vector_type(4)));
typedef __hip_bfloat16 bhalf;
typedef unsigned long long u64;

#define MFMA(a,b,c) __builtin_amdgcn_mfma_f32_16x16x32_bf16((a),(b),(c),0,0,0)

__device__ __forceinline__ float sigm(float x) { return 1.f / (1.f + __expf(-x)); }
__device__ __forceinline__ float tanh_f(float x) { return 1.f - 2.f / (__expf(2.f * x) + 1.f); }

// ---- coherent h-load: plain global_load with sc0 sc1 (same L1/L2-bypass bits
// the atomic load lowers to) but batchable: issue many, wait ONCE.  The atomic
// version (rounds 6/7) serialized one ~430cy L3 round-trip per 8B  -> 11.5us/step.
#define COH_LD(dst, base, imm)                                            \
  asm volatile("global_load_dwordx4 %0, %1, off offset:%2 sc0 sc1"        \
               : "=v"(dst) : "v"(base), "i"(imm))

__device__ __forceinline__ void coh_st_h(bhalf* p, float v) {
  union { bhalf b; unsigned short s; } u;
  u.b = __float2bfloat16(v);
  __hip_atomic_store((unsigned short*)p, u.s, __ATOMIC_RELAXED, __HIP_MEMORY_SCOPE_AGENT);
}
__device__ __forceinline__ void coh_st_f(float* p, float v) {
  __hip_atomic_store(p, v, __ATOMIC_RELAXED, __HIP_MEMORY_SCOPE_AGENT);
}
__device__ __forceinline__ float coh_ld_f(const float* p) {
  return __hip_atomic_load((const float*)p, __ATOMIC_RELAXED, __HIP_MEMORY_SCOPE_AGENT);
}

// ---- grid barrier, no cache-invalidating fence (h goes via coherent ops) ----
__device__ __forceinline__ void gbar(unsigned* bar, unsigned tgt) {
  __syncthreads();
  if (threadIdx.x == 0) {
    __hip_atomic_fetch_add(bar, 1u, __ATOMIC_RELEASE, __HIP_MEMORY_SCOPE_AGENT);
    while (__hip_atomic_load(bar, __ATOMIC_RELAXED, __HIP_MEMORY_SCOPE_AGENT) < tgt)
      __builtin_amdgcn_s_sleep(1);
  }
  __syncthreads();
  asm volatile("" ::: "memory");
}

__global__ void k_zerobar(unsigned* p) {
  int i = blockIdx.x * 256 + threadIdx.x;
  if (i < 1024)
    __hip_atomic_store(p + i, 0u, __ATOMIC_RELAXED, __HIP_MEMORY_SCOPE_AGENT);
}

// ---------- fp32 -> bf16 conversion with zero padding ----------
__global__ __launch_bounds__(256) void k_convert(const float* __restrict__ src,
        bhalf* __restrict__ dst, int rows_in, int cols_in, int cols_out, int total) {
  int i = blockIdx.x * 256 + threadIdx.x;
  if (i >= total) return;
  int r = i / cols_out, c = i - r * cols_out;
  float v = (r < rows_in && c < cols_in) ? src[(size_t)r * cols_in + c] : 0.f;
  dst[i] = __float2bfloat16(v);
}

// ---------- pack Whh [3H][H] -> [(j>>4)*48 + g*16 + (j&15)][k] bf16 ----------
__global__ __launch_bounds__(256) void k_pack(const float* __restrict__ whh,
                                              bhalf* __restrict__ dst) {
  int i = blockIdx.x * 256 + threadIdx.x;
  if (i >= G3 * HID) return;
  int k  = i & (HID - 1);
  int rp = i >> 10;
  int jg  = rp / 48;
  int rem = rp - jg * 48;
  int g = rem >> 4, jl = rem & 15;
  int j = (jg << 4) + jl;
  dst[i] = __float2bfloat16(whh[(size_t)((g << 10) + j) * HID + k]);
}

// ---------- MFMA GEMM-NT, XCD-chunked swizzle; OUTBF: bf16 C vs f32 C ----------
template<int OUTBF>
__global__ __launch_bounds__(256) void k_gemm(
    const bhalf* __restrict__ A, const bhalf* __restrict__ B,
    const float* __restrict__ bias, float* __restrict__ Cf, bhalf* __restrict__ Cb,
    int M, int K, int Nstore) {
  int gx = gridDim.x;
  int nwg = gx * gridDim.y;
  int orig = blockIdx.y * gx + blockIdx.x;
  int xcd = orig & 7, sl = orig >> 3;
  int qq = nwg >> 3, rr = nwg & 7;
  int nbid = (xcd < rr ? xcd * (qq + 1) : rr * (qq + 1) + (xcd - rr) * qq) + sl;
  int bx = nbid % gx, by = nbid / gx;

  int tid = threadIdx.x;
  int l = tid & 63, w = tid >> 6;
  int q = l >> 4, jl = l & 15;
  int n0 = bx * 32;
  int m0 = by * 128 + w * 32;
  int ar0 = m0 + jl;       if (ar0 >= M) ar0 = M - 1;
  int ar1 = m0 + 16 + jl;  if (ar1 >= M) ar1 = M - 1;
  const bhalf* pa0 = A + (size_t)ar0 * K + q * 8;
  const bhalf* pa1 = A + (size_t)ar1 * K + q * 8;
  const bhalf* pb0 = B + (size_t)(n0 + jl) * K + q * 8;
  const bhalf* pb1 = B + (size_t)(n0 + 16 + jl) * K + q * 8;
  f32x4 acc[2][2] = {};
#pragma unroll 4
  for (int kc = 0; kc < K; kc += 32) {
    bf16x8 a0 = *(const bf16x8*)(pa0 + kc);
    bf16x8 a1 = *(const bf16x8*)(pa1 + kc);
    bf16x8 b0 = *(const bf16x8*)(pb0 + kc);
    bf16x8 b1 = *(const bf16x8*)(pb1 + kc);
    acc[0][0] = MFMA(a0, b0, acc[0][0]);
    acc[0][1] = MFMA(a0, b1, acc[0][1]);
    acc[1][0] = MFMA(a1, b0, acc[1][0]);
    acc[1][1] = MFMA(a1, b1, acc[1][1]);
  }
#pragma unroll
  for (int sub = 0; sub < 2; ++sub)
#pragma unroll
    for (int ns = 0; ns < 2; ++ns)
#pragma unroll
      for (int reg = 0; reg < 4; ++reg) {
        int row = m0 + sub * 16 + q * 4 + reg;
        int col = n0 + ns * 16 + jl;
        if (row < M && col < Nstore) {
          float v = acc[sub][ns][reg] + bias[col];
          if (OUTBF) Cb[(size_t)row * Nstore + col] = __float2bfloat16(v);
          else       Cf[(size_t)row * Nstore + col] = v;
        }
      }
}

// ---------- persistent kernel ----------
// 256 blocks x 256 thr, 1 block/CU (132KB LDS). Block owns 16 j-cols; weights
// (48x1024 bf16 = 96KB) in XOR-swizzled LDS. 4 waves split K (256 each),
// partials reduced via 36KB LDS slab. Domain = 64 blocks. h exchanged with
// coherent stores + BATCHED sc0sc1 loads (single vmcnt wait per step).
struct SeqArgs {
  const bhalf *packF, *packB, *packD;
  const bhalf *tabF, *tabB, *tabD;   // bf16 gi tables (bih folded)
  const float *bhhF, *bhhB, *bhhD;
  const int *in_text, *poses;
  bhalf *hb0F, *hb1F, *hb0B, *hb1B;  // enc bf16 h ping-pong, per dir
  float *hfinF, *hfinB;              // enc final fp32 h
  bhalf *h0bf;                       // dec_h0 bf16
  bhalf *hs;                         // [90][128][1024] decoder hidden chain
  unsigned *barF, *barE, *barD;      // full / encoder-domain / decoder-domain
};

__device__ __forceinline__ void load_w(char* wlds, const bhalf* wsrc, int tid) {
  // 48 rows x 1024 cols bf16, 16B chunks, XOR-swizzle byte ^= (row&7)<<4
  for (int it = tid; it < 6144; it += 256) {
    int row = it >> 7, c8 = it & 127;
    int off = (row * 1024 + c8 * 8) * 2;
    *(bf16x8*)(wlds + (off ^ ((row & 7) << 4))) =
        *(const bf16x8*)(wsrc + row * 1024 + c8 * 8);
  }
}

__device__ __forceinline__ bf16x8 ldsB(const char* wlds, int row, int kcol) {
  int off = (row * 1024 + kcol) * 2;
  return *(const bf16x8*)(wlds + (off ^ ((row & 7) << 4)));
}

__global__ __launch_bounds__(256) __attribute__((amdgpu_waves_per_eu(1, 1)))
void k_seq(SeqArgs A) {
  __shared__ char  wlds[96 * 1024];
  __shared__ f32x4 part[3][4][3][64];   // writer-slot, m-tile, gate, lane
  int tid = threadIdx.x;
  int l = tid & 63, w = tid >> 6;       // wave 0..3 = K-quarter
  int q = l >> 4, jl = l & 15;
  int bid = blockIdx.x;
  int kbase = w * 256;

  // ===== encoder mapping: bid = dir*128 + mg*64 + jb =====
  int dir = bid >> 7;
  int mg  = (bid >> 6) & 1;
  int dom = bid >> 6;                   // 0..3
  int jb  = bid & 63;
  int m0  = mg * 64;
  int j   = jb * 16 + jl;
  const bhalf* Bp  = dir ? A.packB : A.packF;
  const bhalf* tab = dir ? A.tabB  : A.tabF;
  const float* bhh = dir ? A.bhhB  : A.bhhF;
  bhalf* hpp0 = dir ? A.hb0B : A.hb0F;
  bhalf* hpp1 = dir ? A.hb1B : A.hb1F;
  unsigned* myE = A.barE + (size_t)dom * 32;
  float bhr = bhh[j], bhz = bhh[HID + j], bhn = bhh[2 * HID + j];

  load_w(wlds, Bp + (size_t)jb * 48 * 1024, tid);

  // zero owner slice of ping buffer 0; fp32 h master in hreg (owner wave = w)
  float hreg[4] = {};
#pragma unroll
  for (int reg = 0; reg < 4; ++reg)
    coh_st_h(&hpp0[(size_t)(m0 + w * 16 + q * 4 + reg) * HID + j], 0.f);
  gbar(A.barF, NBLK);   // also covers LDS weight visibility (syncthreads inside)

  // ===== encoder: 64 steps =====
  unsigned et = 0;
  for (int t = 0; t < TIN; ++t) {
    const bhalf* hcur = (t & 1) ? hpp1 : hpp0;
    bhalf*       hnxt = (t & 1) ? hpp0 : hpp1;
    // early-issue tok -> gi chain (normal cached loads; drain under the wait)
    float gir[4], giz[4], gin[4];
#pragma unroll
    for (int reg = 0; reg < 4; ++reg) {
      int m = m0 + w * 16 + q * 4 + reg;
      int tok = A.in_text[m * TIN + t];
      const bhalf* gi = tab + (size_t)tok * G3;
      gir[reg] = __bfloat162float(gi[j]);
      giz[reg] = __bfloat162float(gi[HID + j]);
      gin[reg] = __bfloat162float(gi[2 * HID + j]);
    }
    // batched coherent A-loads: 32 x 16B in flight, ONE wait
    bf16x8 a0_[8], a1_[8], a2_[8], a3_[8];
    {
      const char* pm0 = (const char*)(hcur + (size_t)(m0 + jl) * HID + kbase + q * 8);
      const char* pm1 = pm0 + 16 * HID * 2;
      const char* pm2 = pm0 + 32 * HID * 2;
      const char* pm3 = pm0 + 48 * HID * 2;
#pragma unroll
      for (int i = 0; i < 8; ++i) {
        COH_LD(a0_[i], pm0, i * 64);
        COH_LD(a1_[i], pm1, i * 64);
        COH_LD(a2_[i], pm2, i * 64);
        COH_LD(a3_[i], pm3, i * 64);
      }
    }
    asm volatile("s_waitcnt vmcnt(0)" ::: "memory");
    __builtin_amdgcn_sched_barrier(0);   // rule #18: pin consumers after wait
    f32x4 acc[4][3] = {};
#pragma unroll
    for (int i = 0; i < 8; ++i) {
      bf16x8 b0 = ldsB(wlds,      jl, kbase + i * 32 + q * 8);
      bf16x8 b1 = ldsB(wlds, 16 + jl, kbase + i * 32 + q * 8);
      bf16x8 b2 = ldsB(wlds, 32 + jl, kbase + i * 32 + q * 8);
      acc[0][0] = MFMA(a0_[i], b0, acc[0][0]);
      acc[0][1] = MFMA(a0_[i], b1, acc[0][1]);
      acc[0][2] = MFMA(a0_[i], b2, acc[0][2]);
      acc[1][0] = MFMA(a1_[i], b0, acc[1][0]);
      acc[1][1] = MFMA(a1_[i], b1, acc[1][1]);
      acc[1][2] = MFMA(a1_[i], b2, acc[1][2]);
      acc[2][0] = MFMA(a2_[i], b0, acc[2][0]);
      acc[2][1] = MFMA(a2_[i], b1, acc[2][1]);
      acc[2][2] = MFMA(a2_[i], b2, acc[2][2]);
      acc[3][0] = MFMA(a3_[i], b0, acc[3][0]);
      acc[3][1] = MFMA(a3_[i], b1, acc[3][1]);
      acc[3][2] = MFMA(a3_[i], b2, acc[3][2]);
    }
    // write partials for non-owned m-tiles (static mt indices; rule #20 safe)
#pragma unroll
    for (int mt = 0; mt < 4; ++mt) {
      if (mt != w) {
        int wi = w - (w > mt ? 1 : 0);
        part[wi][mt][0][l] = acc[mt][0];
        part[wi][mt][1][l] = acc[mt][1];
        part[wi][mt][2][l] = acc[mt][2];
      }
    }
    __syncthreads();
    // owner wave (mt == w): reduce + gates + coherent store
    f32x4 f0 = {}, f1 = {}, f2 = {};
#pragma unroll
    for (int mt = 0; mt < 4; ++mt)
      if (mt == w) { f0 = acc[mt][0]; f1 = acc[mt][1]; f2 = acc[mt][2]; }
#pragma unroll
    for (int s = 0; s < 3; ++s) {
      f0 += part[s][w][0][l]; f1 += part[s][w][1][l]; f2 += part[s][w][2][l];
    }
#pragma unroll
    for (int reg = 0; reg < 4; ++reg) {
      float r = sigm(gir[reg] + f0[reg] + bhr);
      float z = sigm(giz[reg] + f1[reg] + bhz);
      float n = tanh_f(gin[reg] + r * (f2[reg] + bhn));
      float hv = (1.f - z) * n + z * hreg[reg];
      hreg[reg] = hv;
      coh_st_h(&hnxt[(size_t)(m0 + w * 16 + q * 4 + reg) * HID + j], hv);
    }
    et += 64;
    if (t < TIN - 1) gbar(myE, et);
  }

  // ===== handoff: final fp32 h -> hfin; full barrier =====
  {
    float* hfin = dir ? A.hfinB : A.hfinF;
#pragma unroll
    for (int reg = 0; reg < 4; ++reg)
      coh_st_f(&hfin[(size_t)(m0 + w * 16 + q * 4 + reg) * HID + j], hreg[reg]);
  }
  gbar(A.barF, 2 * NBLK);

  // ===== decoder mapping: bid = dom2*64 + jb2; 32 rows, 2 m-tiles =====
  int dom2 = bid >> 6;
  int jb2  = bid & 63;
  int m20  = dom2 * 32;
  int j2   = jb2 * 16 + jl;
  unsigned* myD = A.barD + (size_t)dom2 * 32;
  float b2r = A.bhhD[j2], b2z = A.bhhD[HID + j2], b2n = A.bhhD[2 * HID + j2];

  load_w(wlds, A.packD + (size_t)jb2 * 48 * 1024, tid);

  float hreg4[4];
  if (w < 2) {
#pragma unroll
    for (int reg = 0; reg < 4; ++reg) {
      int m = m20 + w * 16 + q * 4 + reg;
      float s = coh_ld_f(&A.hfinF[(size_t)m * HID + j2]) +
                coh_ld_f(&A.hfinB[(size_t)m * HID + j2]);
      hreg4[reg] = s;
      coh_st_h(&A.h0bf[(size_t)m * HID + j2], s);
    }
  }
  unsigned dt = 64;
  gbar(myD, dt);   // h0bf + decoder LDS weights visible

  // ===== decoder: 90 steps; bf16 h written straight into hs slab =====
  for (int t = 0; t < TOUT; ++t) {
    const bhalf* Asrc = t ? (A.hs + (size_t)(t - 1) * BH) : A.h0bf;
    int pt = t ? t - 1 : 0;
    float gir[4], giz[4], gin[4];
    if (w < 2) {
#pragma unroll
      for (int reg = 0; reg < 4; ++reg) {
        int m = m20 + w * 16 + q * 4 + reg;
        int tok = A.poses[m * TOUT + pt];
        const bhalf* gi = A.tabD + (size_t)tok * G3;
        gir[reg] = __bfloat162float(gi[j2]);
        giz[reg] = __bfloat162float(gi[HID + j2]);
        gin[reg] = __bfloat162float(gi[2 * HID + j2]);
      }
    }
    bf16x8 a0_[8], a1_[8];
    {
      const char* pm0 = (const char*)(Asrc + (size_t)(m20 + jl) * HID + kbase + q * 8);
      const char* pm1 = pm0 + 16 * HID * 2;
#pragma unroll
      for (int i = 0; i < 8; ++i) {
        COH_LD(a0_[i], pm0, i * 64);
        COH_LD(a1_[i], pm1, i * 64);
      }
    }
    asm volatile("s_waitcnt vmcnt(0)" ::: "memory");
    __builtin_amdgcn_sched_barrier(0);
    f32x4 acc[2][3] = {};
#pragma unroll
    for (int i = 0; i < 8; ++i) {
      bf16x8 b0 = ldsB(wlds,      jl, kbase + i * 32 + q * 8);
      bf16x8 b1 = ldsB(wlds, 16 + jl, kbase + i * 32 + q * 8);
      bf16x8 b2 = ldsB(wlds, 32 + jl, kbase + i * 32 + q * 8);
      acc[0][0] = MFMA(a0_[i], b0, acc[0][0]);
      acc[0][1] = MFMA(a0_[i], b1, acc[0][1]);
      acc[0][2] = MFMA(a0_[i], b2, acc[0][2]);
      acc[1][0] = MFMA(a1_[i], b0, acc[1][0]);
      acc[1][1] = MFMA(a1_[i], b1, acc[1][1]);
      acc[1][2] = MFMA(a1_[i], b2, acc[1][2]);
    }
#pragma unroll
    for (int mt = 0; mt < 2; ++mt) {
      if (mt != w) {
        int wi = w - (w > mt ? 1 : 0);
        part[wi][mt][0][l] = acc[mt][0];
        part[wi][mt][1][l] = acc[mt][1];
        part[wi][mt][2][l] = acc[mt][2];
      }
    }
    __syncthreads();
    if (w < 2) {
      f32x4 f0 = {}, f1 = {}, f2 = {};
#pragma unroll
      for (int mt = 0; mt < 2; ++mt)
        if (mt == w) { f0 = acc[mt][0]; f1 = acc[mt][1]; f2 = acc[mt][2]; }
#pragma unroll
      for (int s = 0; s < 3; ++s) {
        f0 += part[s][w][0][l]; f1 += part[s][w][1][l]; f2 += part[s][w][2][l];
      }
      bhalf* hout = A.hs + (size_t)t * BH;
#pragma unroll
      for (int reg = 0; reg < 4; ++reg) {
        float r = sigm(gir[reg] + f0[reg] + b2r);
        float z = sigm(giz[reg] + f1[reg] + b2z);
        float n = tanh_f(gin[reg] + r * (f2[reg] + b2n));
        float hv = (1.f - z) * n + z * hreg4[reg];
        hreg4[reg] = hv;
        coh_st_h(&hout[(size_t)(m20 + w * 16 + q * 4 + reg) * HID + j2], hv);
      }
    }
    dt += 64;
    if (t < TOUT - 1) gbar(myD, dt);
  }
}

extern "C" void kernel_launch(void* const* d_in, const int* in_sizes, int n_in,
                              void* d_out, int out_size, void* d_ws, size_t ws_size,
                              hipStream_t stream) {
  const float* enc_emb   = (const float*)d_in[0];
  const float* enc_Wih_f = (const float*)d_in[1];
  const float* enc_Whh_f = (const float*)d_in[2];
  const float* enc_bih_f = (const float*)d_in[3];
  const float* enc_bhh_f = (const float*)d_in[4];
  const float* enc_Wih_b = (const float*)d_in[5];
  const float* enc_Whh_b = (const float*)d_in[6];
  const float* enc_bih_b = (const float*)d_in[7];
  const float* enc_bhh_b = (const float*)d_in[8];
  const float* dec_emb   = (const float*)d_in[9];
  const float* dec_Wih   = (const float*)d_in[10];
  const float* dec_Whh   = (const float*)d_in[11];
  const float* dec_bih   = (const float*)d_in[12];
  const float* dec_bhh   = (const float*)d_in[13];
  const float* fc_W      = (const float*)d_in[14];
  const float* fc_b      = (const float*)d_in[15];
  const int*   in_text   = (const int*)d_in[16];
  const int*   poses     = (const int*)d_in[18];
  float* out = (float*)d_out;

  char* p = (char*)d_ws;
  auto alloc = [&](size_t n) { char* r = p; p += (n + 255) & ~(size_t)255; return r; };
  bhalf* tabF  = (bhalf*)alloc((size_t)VOCAB * G3 * 2);
  bhalf* tabB  = (bhalf*)alloc((size_t)VOCAB * G3 * 2);
  bhalf* tabD  = (bhalf*)alloc((size_t)POSE * G3 * 2);
  bhalf* hb0F  = (bhalf*)alloc(BH * 2);
  bhalf* hb1F  = (bhalf*)alloc(BH * 2);
  bhalf* hb0B  = (bhalf*)alloc(BH * 2);
  bhalf* hb1B  = (bhalf*)alloc(BH * 2);
  float* hfinF = (float*)alloc(BH * 4);
  float* hfinB = (float*)alloc(BH * 4);
  bhalf* h0bf  = (bhalf*)alloc(BH * 2);
  bhalf* hs    = (bhalf*)alloc((size_t)TOUT * BH * 2);
  bhalf* embbf = (bhalf*)alloc((size_t)VOCAB * EMBP * 2);
  bhalf* wihF  = (bhalf*)alloc((size_t)G3 * EMBP * 2);
  bhalf* wihB  = (bhalf*)alloc((size_t)G3 * EMBP * 2);
  bhalf* dembbf= (bhalf*)alloc((size_t)POSE * HID * 2);
  bhalf* dwih  = (bhalf*)alloc((size_t)G3 * HID * 2);
  bhalf* fcw   = (bhalf*)alloc((size_t)544 * HID * 2);
  bhalf* packF = (bhalf*)alloc((size_t)G3 * HID * 2);
  bhalf* packB = (bhalf*)alloc((size_t)G3 * HID * 2);
  bhalf* packD = (bhalf*)alloc((size_t)G3 * HID * 2);
  unsigned* bars = (unsigned*)alloc(4096);
  unsigned* barF = bars;               // 1 counter (padded)
  unsigned* barE = bars + 32;          // 4 domain counters x 32 uints
  unsigned* barD = bars + 32 + 4 * 32; // 4 domain counters

  auto cgrid = [](int total) { return dim3((total + 255) / 256); };

  // one-off conversions / packing (+ barrier counters zero)
  k_zerobar<<<dim3(4), 256, 0, stream>>>(bars);
  k_convert<<<cgrid(VOCAB * EMBP), 256, 0, stream>>>(enc_emb, embbf, VOCAB, EMB, EMBP, VOCAB * EMBP);
  k_convert<<<cgrid(G3 * EMBP),   256, 0, stream>>>(enc_Wih_f, wihF, G3, EMB, EMBP, G3 * EMBP);
  k_convert<<<cgrid(G3 * EMBP),   256, 0, stream>>>(enc_Wih_b, wihB, G3, EMB, EMBP, G3 * EMBP);
  k_convert<<<cgrid(POSE * HID),  256, 0, stream>>>(dec_emb, dembbf, POSE, HID, HID, POSE * HID);
  k_convert<<<cgrid(G3 * HID),    256, 0, stream>>>(dec_Wih, dwih, G3, HID, HID, G3 * HID);
  k_convert<<<cgrid(544 * HID),   256, 0, stream>>>(fc_W, fcw, POSE, HID, HID, 544 * HID);
  k_pack<<<cgrid(G3 * HID), 256, 0, stream>>>(enc_Whh_f, packF);
  k_pack<<<cgrid(G3 * HID), 256, 0, stream>>>(enc_Whh_b, packB);
  k_pack<<<cgrid(G3 * HID), 256, 0, stream>>>(dec_Whh, packD);

  // gi tables (bf16, bih folded)
  k_gemm<1><<<dim3(96, 31), 256, 0, stream>>>(embbf, wihF, enc_bih_f, nullptr, tabF, VOCAB, EMBP, G3);
  k_gemm<1><<<dim3(96, 31), 256, 0, stream>>>(embbf, wihB, enc_bih_b, nullptr, tabB, VOCAB, EMBP, G3);
  k_gemm<1><<<dim3(96, 5),  256, 0, stream>>>(dembbf, dwih, dec_bih, nullptr, tabD, POSE, HID, G3);

  // persistent enc+dec
  SeqArgs sa;
  sa.packF = packF; sa.packB = packB; sa.packD = packD;
  sa.tabF = tabF; sa.tabB = tabB; sa.tabD = tabD;
  sa.bhhF = enc_bhh_f; sa.bhhB = enc_bhh_b; sa.bhhD = dec_bhh;
  sa.in_text = in_text; sa.poses = poses;
  sa.hb0F = hb0F; sa.hb1F = hb1F; sa.hb0B = hb0B; sa.hb1B = hb1B;
  sa.hfinF = hfinF; sa.hfinB = hfinB; sa.h0bf = h0bf; sa.hs = hs;
  sa.barF = barF; sa.barE = barE; sa.barD = barD;
  k_seq<<<dim3(NBLK), dim3(256), 0, stream>>>(sa);

  // output projection
  k_gemm<0><<<dim3(17, 90), 256, 0, stream>>>(hs, fcw, fc_b, out, nullptr, TOUT * BATCH, HID, POSE);
}